// Round 5
// baseline (881.074 us; speedup 1.0000x reference)
//
#include <hip/hip_runtime.h>

// SubjBasisGenerator fused pipeline. B=4 NQ=416 NC=257 D=768 H=6 DH=128 G=104 R=4 LORA=64
//
// R5: R4's design (device-side dtype probe + flag-dispatched external loads)
// with the 4-arg-dropped launch_gemm calls fixed (Z=1 restored).
//
// Algebra: out = LN((attn-combined)@Wo). The grouped-conv+LN v-path decomposes
// exactly so the (B,G,NC,768) tensor is never materialized:
//   sum_j A_j v_j = gv2*( (sum_j A_j inv_j mid_j)@Wconv[g] - sum_j A_j inv_j mu_j )
//                   + bv2 + (A @ ctx)
// with mu,inv per (b,g,j) from wbar[g] and the per-group Gram matrix.

typedef unsigned short u16;
typedef unsigned int   u32;
typedef __attribute__((ext_vector_type(4))) float f32x4;
typedef __attribute__((ext_vector_type(4))) u32   u32x4;
typedef __attribute__((ext_vector_type(8))) short bf16x8;

__device__ __forceinline__ float bf2f(u16 v) { return __uint_as_float(((u32)v) << 16); }
__device__ __forceinline__ u16 f2bf(float f) {
  u32 u = __float_as_uint(f);
  u32 r = u + 0x7fffu + ((u >> 16) & 1u);  // RNE
  return (u16)(r >> 16);
}
// dtype-flag-dispatched external load (element index, not bytes)
__device__ __forceinline__ float gld(const void* p, long idx, int f32) {
  return f32 ? ((const float*)p)[idx] : bf2f(((const u16*)p)[idx]);
}

// ------------------------------------------------------------ dtype probe ---
// Packed-bf16 data: low u16 of each word is a bf16 ~N(0,1) value -> |v| in
// [1e-3,32] (or 0) with P~0.999. fp32 data: low u16 = mantissa bits, uniform
// exponent when viewed as bf16 -> P~0.06. Count over 4096 words of x.
__global__ __launch_bounds__(256) void probe_k(const u32* __restrict__ xw, int* __restrict__ flag) {
  int tid = threadIdx.x, c = 0;
  for (int i = tid; i < 4096; i += 256) {
    u16 lo = (u16)(xw[i] & 0xffffu);
    float a = fabsf(bf2f(lo));
    if (lo == 0 || (a >= 1e-3f && a <= 32.f)) ++c;
  }
#pragma unroll
  for (int o = 32; o; o >>= 1) c += __shfl_xor(c, o, 64);
  __shared__ int r[4];
  if ((tid & 63) == 0) r[tid >> 6] = c;
  __syncthreads();
  if (tid == 0) flag[0] = (r[0] + r[1] + r[2] + r[3] >= 2048) ? 0 : 1;  // 1 = fp32
}

// ------------------------------------------------------------ diag fill -----
__global__ __launch_bounds__(256) void fill_k(u16* p, float v, int n) {
  int i = blockIdx.x * 256 + threadIdx.x;
  if (i < n) p[i] = f2bf(v);
}

// ---------------------------------------------------------------- GEMM ------
// C = alpha*(A@B); A/B external-or-internal selected per-operand: aSel/bSel=1
// means "follow dtype flag", 0 means always-bf16 (internal). C fp32 (Cf) or
// bf16 (Cb). Batched via blockIdx.z. btrans: B stored N-major (A @ B^T).
// 64x64 tile, BK=32, 4 waves, 2x2 mfma_f32_16x16x32_bf16 per wave.
#define LDS_S 40

__global__ __launch_bounds__(256) void gemm_bf16(
    const void* __restrict__ A, const void* __restrict__ B,
    float* __restrict__ Cf, u16* __restrict__ Cb, int obf,
    int M, int N, int K, int lda, int ldb, int ldc,
    long sA, long sBo, long sBi, int bdiv, long sC, int btrans, float alpha,
    const int* __restrict__ dtf, int aSel, int bSel)
{
  const int f = dtf[0];
  const int af32 = aSel & f, bf32 = bSel & f;
  int z = blockIdx.z;
  const long aoff = (long)z * sA;
  const long boff = (long)(z / bdiv) * sBo + (long)(z % bdiv) * sBi;
  const u16*   A16 = (const u16*)A + aoff;
  const float* A32 = (const float*)A + aoff;
  const u16*   B16 = (const u16*)B + boff;
  const float* B32 = (const float*)B + boff;

  __shared__ __attribute__((aligned(16))) u16 As[64 * LDS_S];
  __shared__ __attribute__((aligned(16))) u16 Bs[64 * LDS_S];

  const int tid = threadIdx.x;
  const int lane = tid & 63, wave = tid >> 6;
  const int m0 = blockIdx.x * 64, n0 = blockIdx.y * 64;
  const int wm = (wave >> 1) * 32, wn = (wave & 1) * 32;
  const int fm = lane & 15, fq = lane >> 4;

  const int ar = tid >> 2, ak = (tid & 3) * 8;   // A staging: row, k-offset
  const int bk = tid >> 3, bn = (tid & 7) * 8;   // B staging (non-trans path)

  f32x4 acc[2][2];
  const f32x4 zero4 = {0.f, 0.f, 0.f, 0.f};
#pragma unroll
  for (int a_ = 0; a_ < 2; ++a_)
#pragma unroll
    for (int b_ = 0; b_ < 2; ++b_) acc[a_][b_] = zero4;

  for (int k0 = 0; k0 < K; k0 += 32) {
    // ---- stage A tile (64 x 32) ----
    {
      int gm = m0 + ar, gk = k0 + ak;
      long idx = (long)gm * lda + gk;
      if (gm < M && gk + 8 <= K) {
        if (af32) {
          f32x4 u = *(const f32x4*)(A32 + idx), v = *(const f32x4*)(A32 + idx + 4);
          u32x4 q = { (u32)f2bf(u.x) | ((u32)f2bf(u.y) << 16),
                      (u32)f2bf(u.z) | ((u32)f2bf(u.w) << 16),
                      (u32)f2bf(v.x) | ((u32)f2bf(v.y) << 16),
                      (u32)f2bf(v.z) | ((u32)f2bf(v.w) << 16) };
          *(u32x4*)&As[ar * LDS_S + ak] = q;
        } else {
          *(u32x4*)&As[ar * LDS_S + ak] = *(const u32x4*)(A16 + idx);
        }
      } else {
#pragma unroll
        for (int e = 0; e < 8; ++e) {
          u16 v = 0;
          if (gm < M && gk + e < K) v = f2bf(gld(A, aoff + idx + e, af32));
          As[ar * LDS_S + ak + e] = v;
        }
      }
    }
    // ---- stage B tile as Bs[n][k] (64 x 32) ----
    if (btrans) {
      int gn = n0 + ar, gk = k0 + ak;
      long idx = (long)gn * ldb + gk;
      if (gk + 8 <= K) {
        if (bf32) {
          f32x4 u = *(const f32x4*)(B32 + idx), v = *(const f32x4*)(B32 + idx + 4);
          u32x4 q = { (u32)f2bf(u.x) | ((u32)f2bf(u.y) << 16),
                      (u32)f2bf(u.z) | ((u32)f2bf(u.w) << 16),
                      (u32)f2bf(v.x) | ((u32)f2bf(v.y) << 16),
                      (u32)f2bf(v.z) | ((u32)f2bf(v.w) << 16) };
          *(u32x4*)&Bs[ar * LDS_S + ak] = q;
        } else {
          *(u32x4*)&Bs[ar * LDS_S + ak] = *(const u32x4*)(B16 + idx);
        }
      } else {
#pragma unroll
        for (int e = 0; e < 8; ++e) {
          u16 v = 0;
          if (gk + e < K) v = f2bf(gld(B, boff + idx + e, bf32));
          Bs[ar * LDS_S + ak + e] = v;
        }
      }
    } else {
      int gk = k0 + bk;
      long idx = (long)gk * ldb + n0 + bn;
      u16 tmp[8];
      if (gk < K) {
        if (bf32) {
          f32x4 u = *(const f32x4*)(B32 + idx), v = *(const f32x4*)(B32 + idx + 4);
          tmp[0] = f2bf(u.x); tmp[1] = f2bf(u.y); tmp[2] = f2bf(u.z); tmp[3] = f2bf(u.w);
          tmp[4] = f2bf(v.x); tmp[5] = f2bf(v.y); tmp[6] = f2bf(v.z); tmp[7] = f2bf(v.w);
        } else {
          u32x4 v = *(const u32x4*)(B16 + idx);
          tmp[0] = (u16)(v.x & 0xffff); tmp[1] = (u16)(v.x >> 16);
          tmp[2] = (u16)(v.y & 0xffff); tmp[3] = (u16)(v.y >> 16);
          tmp[4] = (u16)(v.z & 0xffff); tmp[5] = (u16)(v.z >> 16);
          tmp[6] = (u16)(v.w & 0xffff); tmp[7] = (u16)(v.w >> 16);
        }
      } else {
#pragma unroll
        for (int e = 0; e < 8; ++e) tmp[e] = 0;
      }
      int rot = tid & 7;  // spread LDS bank writes
#pragma unroll
      for (int e = 0; e < 8; ++e) {
        int ee = (e + rot) & 7;
        Bs[(bn + ee) * LDS_S + bk] = tmp[ee];
      }
    }
    __syncthreads();
    {
      bf16x8 fa[2], fb[2];
      fa[0] = *(const bf16x8*)&As[(wm +      fm) * LDS_S + fq * 8];
      fa[1] = *(const bf16x8*)&As[(wm + 16 + fm) * LDS_S + fq * 8];
      fb[0] = *(const bf16x8*)&Bs[(wn +      fm) * LDS_S + fq * 8];
      fb[1] = *(const bf16x8*)&Bs[(wn + 16 + fm) * LDS_S + fq * 8];
#pragma unroll
      for (int mt = 0; mt < 2; ++mt)
#pragma unroll
        for (int nt = 0; nt < 2; ++nt)
          acc[mt][nt] = __builtin_amdgcn_mfma_f32_16x16x32_bf16(fa[mt], fb[nt], acc[mt][nt], 0, 0, 0);
    }
    __syncthreads();
  }
  // epilogue: C/D layout col=lane&15, row=(lane>>4)*4+reg (m89-verified)
#pragma unroll
  for (int mt = 0; mt < 2; ++mt)
#pragma unroll
    for (int nt = 0; nt < 2; ++nt)
#pragma unroll
      for (int rr = 0; rr < 4; ++rr) {
        int gm = m0 + wm + mt * 16 + fq * 4 + rr;
        int gn = n0 + wn + nt * 16 + fm;
        if (gm < M) {
          float v = alpha * acc[mt][nt][rr];
          if (obf) Cb[(long)z * sC + (long)gm * ldc + gn] = f2bf(v);
          else     Cf[(long)z * sC + (long)gm * ldc + gn] = v;
        }
      }
}

// ------------------------------------------------------------- row LN -------
// in: bf16. g/b: external (flag dtype). out: bf16 normally; final call writes
// d_out in the flag dtype. in==out allowed for bf16 mode (same-thread RMW).
__global__ __launch_bounds__(256) void ln_rows(
    const u16* __restrict__ in, const void* __restrict__ g, const void* __restrict__ b,
    void* __restrict__ out, int N, const int* __restrict__ dtf, int isfinal)
{
  const int f = dtf[0];
  long row = blockIdx.x;
  const u16* ip = in + row * N;
  int tid = threadIdx.x, lane = tid & 63, wave = tid >> 6;
  float s1 = 0.f, s2 = 0.f;
  for (int c = tid; c < N; c += 256) { float v = bf2f(ip[c]); s1 += v; s2 += v * v; }
#pragma unroll
  for (int o = 32; o; o >>= 1) { s1 += __shfl_xor(s1, o, 64); s2 += __shfl_xor(s2, o, 64); }
  __shared__ float red[8];
  if (lane == 0) { red[wave] = s1; red[4 + wave] = s2; }
  __syncthreads();
  s1 = red[0] + red[1] + red[2] + red[3];
  s2 = red[4] + red[5] + red[6] + red[7];
  float mean = s1 / N;
  float var = s2 / N - mean * mean;
  float rstd = rsqrtf(fmaxf(var, 0.f) + 1e-5f);
  for (int c = tid; c < N; c += 256) {
    float val = (bf2f(ip[c]) - mean) * rstd * gld(g, c, f) + gld(b, c, f);
    if (isfinal && f) ((float*)out)[row * N + c] = val;
    else              ((u16*)out)[row * N + c] = f2bf(val);
  }
}

// ------------------------------------------------------------- wbar ---------
__global__ __launch_bounds__(256) void wbar_k(const void* __restrict__ Wconv,
                                              float* __restrict__ wbar,
                                              const int* __restrict__ dtf)
{
  const int f = dtf[0];
  int g = blockIdx.x;
  int lane = threadIdx.x & 63, wave = threadIdx.x >> 6;
  long base = (long)g * 49152;
  for (int l = wave * 16; l < wave * 16 + 16; ++l) {
    float s = 0.f;
    for (int c = lane; c < 768; c += 64) s += gld(Wconv, base + (long)l * 768 + c, f);
#pragma unroll
    for (int o = 32; o; o >>= 1) s += __shfl_xor(s, o, 64);
    if (lane == 0) wbar[g * 64 + l] = s * (1.f / 768.f);
  }
}

// ------------------------------------------------------------- stats --------
// per (b,g,j): mu = mid.wbar[g]; E[w^2] = mid^T M[g] mid; inv = rsqrt(var+eps)
__global__ __launch_bounds__(256) void stats_k(
    const u16* __restrict__ midbf, const float* __restrict__ Mmat, const float* __restrict__ wbar,
    u16* __restrict__ midi, float* __restrict__ pim)
{
  int g = blockIdx.x;
  int row0 = blockIdx.y * 64;
  int tid = threadIdx.x, lane = tid & 63, wave = tid >> 6;
  __shared__ __attribute__((aligned(16))) float Ms[64 * 68];
  __shared__ __attribute__((aligned(16))) float mrow[4][64];
  __shared__ float wb[64];
  {
    int l1 = tid >> 2, c0 = (tid & 3) * 16;
    const float* src = Mmat + (long)g * 4096 + l1 * 64 + c0;
    float* dst = &Ms[l1 * 68 + c0];
#pragma unroll
    for (int e = 0; e < 16; e += 4) *(f32x4*)(dst + e) = *(const f32x4*)(src + e);
  }
  if (tid < 64) wb[tid] = wbar[g * 64 + tid];
  __syncthreads();
  for (int t = 0; t < 16; ++t) {
    int r = row0 + wave * 16 + t;            // flat (b*257+j) row
    bool valid = r < 1028;
    float m = valid ? bf2f(midbf[(long)r * 6656 + g * 64 + lane]) : 0.f;
    mrow[wave][lane] = m;
    __syncthreads();
    float rowdot = 0.f;
    const f32x4* Mr = (const f32x4*)&Ms[lane * 68];
    const f32x4* xr = (const f32x4*)&mrow[wave][0];
#pragma unroll
    for (int c = 0; c < 16; ++c) {
      f32x4 a = Mr[c], x = xr[c];
      rowdot = fmaf(a.x, x.x, rowdot); rowdot = fmaf(a.y, x.y, rowdot);
      rowdot = fmaf(a.z, x.z, rowdot); rowdot = fmaf(a.w, x.w, rowdot);
    }
    float mup = m * wb[lane];
    float q2p = m * rowdot;
#pragma unroll
    for (int o = 32; o; o >>= 1) { mup += __shfl_xor(mup, o, 64); q2p += __shfl_xor(q2p, o, 64); }
    float var = q2p - mup * mup;
    float inv = rsqrtf(fmaxf(var, 0.f) + 1e-5f);
    if (valid) {
      int bb = r / 257, j = r - bb * 257;
      long base = ((long)bb * 104 + g) * 257 + j;
      midi[base * 64 + lane] = f2bf(inv * m);
      if (lane == 0) pim[base] = inv * mup;
    }
    __syncthreads();
  }
}

// ------------------------------------------------------------- attention ----
#define KS_S 136
__global__ __launch_bounds__(256) void attn_k(
    const u16* __restrict__ qbf, const u16* __restrict__ kbf, const float* __restrict__ pim,
    u16* __restrict__ Abf, u16* __restrict__ A2bf, float* __restrict__ s_sh)
{
  int bh = blockIdx.x;
  int b = bh / 6, h = bh - b * 6;
  int i0 = blockIdx.y * 32;
  int tid = threadIdx.x, lane = tid & 63, wave = tid >> 6;

  __shared__ __attribute__((aligned(16))) u16 qs[32 * KS_S];
  __shared__ __attribute__((aligned(16))) u16 ks[129 * KS_S];

  {  // stage q tile: 32 rows x 128
    int r = tid >> 3, c0 = (tid & 7) * 16;
    const u16* src = qbf + ((long)(b * 416 + i0 + r)) * 768 + h * 128 + c0;
    *(u32x4*)&qs[r * KS_S + c0]     = *(const u32x4*)(src);
    *(u32x4*)&qs[r * KS_S + c0 + 8] = *(const u32x4*)(src + 8);
  }

  float s[8][5];
#pragma unroll
  for (int t = 0; t < 8; ++t)
#pragma unroll
    for (int jc = 0; jc < 5; ++jc) s[t][jc] = 0.f;

  const float sc2 = 0.08838834764831845f;  // DH^-0.5
  typedef __attribute__((ext_vector_type(4))) u32 u32x4t;

#pragma unroll
  for (int ch = 0; ch < 2; ++ch) {
    const int j0 = ch ? 128 : 0;
    const int len = ch ? 129 : 128;
    __syncthreads();
    for (int r = tid >> 3; r < len; r += 32) {
      int c0 = (tid & 7) * 16;
      const u16* src = kbf + ((long)(b * 257 + j0 + r)) * 768 + h * 128 + c0;
      *(u32x4*)&ks[r * KS_S + c0]     = *(const u32x4*)(src);
      *(u32x4*)&ks[r * KS_S + c0 + 8] = *(const u32x4*)(src + 8);
    }
    __syncthreads();
    const int njc = ch ? 3 : 2;
#pragma unroll
    for (int t = 0; t < 8; ++t) {
      int il = wave * 8 + t;
      const u32x4t* qp = (const u32x4t*)&qs[il * KS_S];
#pragma unroll
      for (int jcl = 0; jcl < 3; ++jcl) {
        if (jcl >= njc) break;
        int jl = jcl * 64 + lane;
        if (jl < len) {
          const u32x4t* kp = (const u32x4t*)&ks[jl * KS_S];
          float acc = 0.f;
#pragma unroll
          for (int c = 0; c < 16; ++c) {
            u32x4t kv = kp[c], qv = qp[c];
            acc = fmaf(bf2f((u16)(kv.x & 0xffff)), bf2f((u16)(qv.x & 0xffff)), acc);
            acc = fmaf(bf2f((u16)(kv.x >> 16)),    bf2f((u16)(qv.x >> 16)),    acc);
            acc = fmaf(bf2f((u16)(kv.y & 0xffff)), bf2f((u16)(qv.y & 0xffff)), acc);
            acc = fmaf(bf2f((u16)(kv.y >> 16)),    bf2f((u16)(qv.y >> 16)),    acc);
            acc = fmaf(bf2f((u16)(kv.z & 0xffff)), bf2f((u16)(qv.z & 0xffff)), acc);
            acc = fmaf(bf2f((u16)(kv.z >> 16)),    bf2f((u16)(qv.z >> 16)),    acc);
            acc = fmaf(bf2f((u16)(kv.w & 0xffff)), bf2f((u16)(qv.w & 0xffff)), acc);
            acc = fmaf(bf2f((u16)(kv.w >> 16)),    bf2f((u16)(qv.w >> 16)),    acc);
          }
          s[t][ch ? (2 + jcl) : jcl] = acc * sc2;
        }
      }
    }
  }

#pragma unroll
  for (int t = 0; t < 8; ++t) {
    int il = wave * 8 + t;
    int i = i0 + il;
    int g = i % 104, rq = i / 104;
    float mx = -1e30f;
#pragma unroll
    for (int jc = 0; jc < 5; ++jc) {
      int j = jc * 64 + lane;
      if (j < 257) mx = fmaxf(mx, s[t][jc]);
    }
#pragma unroll
    for (int o = 32; o; o >>= 1) mx = fmaxf(mx, __shfl_xor(mx, o, 64));
    float p[5], sum = 0.f, sp = 0.f;
    long pimb = ((long)b * 104 + g) * 257;
#pragma unroll
    for (int jc = 0; jc < 5; ++jc) {
      int j = jc * 64 + lane;
      float pv = 0.f;
      if (j < 257) { pv = __expf(s[t][jc] - mx); sp = fmaf(pv, pim[pimb + j], sp); }
      p[jc] = pv; sum += pv;
    }
#pragma unroll
    for (int o = 32; o; o >>= 1) { sum += __shfl_xor(sum, o, 64); sp += __shfl_xor(sp, o, 64); }
    float rs = 1.f / sum;
    long arow  = ((long)bh * 416 + i) * 264;
    long a2row = (((long)b * 104 + g) * 24 + h * 4 + rq) * 264;
#pragma unroll
    for (int jc = 0; jc < 5; ++jc) {
      int j = jc * 64 + lane;
      if (j < 257) { u16 pb = f2bf(p[jc] * rs); Abf[arow + j] = pb; A2bf[a2row + j] = pb; }
      else if (j < 264) { Abf[arow + j] = 0; A2bf[a2row + j] = 0; }  // pad
    }
    if (lane == 0) s_sh[(long)bh * 416 + i] = sp * rs;
  }
}

// ------------------------------------------------------------- out epilogue -
__global__ __launch_bounds__(256) void out_core(
    const float* __restrict__ T, const float* __restrict__ s_sh, const float* __restrict__ c_buf,
    const void* __restrict__ Wconv, const void* __restrict__ gv2, const void* __restrict__ bv2,
    u16* __restrict__ opbf, const int* __restrict__ dtf)
{
  const int f = dtf[0];
  int bi = blockIdx.x;
  int b = bi / 416, i = bi - b * 416;
  int g = i % 104, rq = i / 104;
  int tid = threadIdx.x;
  __shared__ float Ts[6 * 64];
  __shared__ float ssh[6];
  for (int idx = tid; idx < 384; idx += 256) {
    int h = idx >> 6, l = idx & 63;
    Ts[idx] = T[(((long)b * 104 + g) * 24 + h * 4 + rq) * 64 + l];
  }
  if (tid < 6) ssh[tid] = s_sh[((long)b * 6 + tid) * 416 + i];
  __syncthreads();
  long wbase = (long)g * 49152;
#pragma unroll
  for (int it = 0; it < 3; ++it) {
    int d = tid + it * 256;
    int h = d >> 7, dh = d & 127;
    float acc = 0.f;
    const float* tp = &Ts[h * 64];
#pragma unroll
    for (int l = 0; l < 64; ++l) acc = fmaf(tp[l], gld(Wconv, wbase + (long)l * 768 + d, f), acc);
    float val = gld(gv2, d, f) * (acc - ssh[h]) + gld(bv2, d, f)
              + c_buf[(((long)b * 6 + h) * 416 + i) * 128 + dh];
    opbf[((long)b * 416 + i) * 768 + d] = f2bf(val);
  }
}

// ---------------------------------------------------------------- host ------
static void launch_gemm(const void* A, const void* B, float* Cf, u16* Cb, int obf,
                        int M, int N, int K, int lda, int ldb, int ldc,
                        long sA, long sBo, long sBi, int bdiv, long sC,
                        int Z, int btrans, float alpha, const int* dtf,
                        int aSel, int bSel, hipStream_t st)
{
  dim3 grid((M + 63) / 64, N / 64, Z);
  gemm_bf16<<<grid, dim3(256), 0, st>>>(A, B, Cf, Cb, obf, M, N, K, lda, ldb, ldc,
                                        sA, sBo, sBi, bdiv, sC, btrans, alpha,
                                        dtf, aSel, bSel);
}

extern "C" void kernel_launch(void* const* d_in, const int* in_sizes, int n_in,
                              void* d_out, int out_size, void* d_ws, size_t ws_size,
                              hipStream_t stream)
{
  (void)in_sizes; (void)n_in;
  const void* x   = d_in[0];
  const void* ctx = d_in[1];
  const void* Wq  = d_in[2];
  const void* gq  = d_in[3];
  const void* bq  = d_in[4];
  const void* Wk  = d_in[5];
  const void* gk  = d_in[6];
  const void* bk  = d_in[7];
  const void* Wv  = d_in[8];
  const void* gv1 = d_in[9];
  const void* bv1 = d_in[10];
  const void* Wcv = d_in[11];
  const void* gv2 = d_in[12];
  const void* bv2 = d_in[13];
  const void* Wo  = d_in[14];
  const void* go  = d_in[15];
  const void* bo  = d_in[16];

  // -------- workspace layout --------
  const size_t SZ_FLAG = 256;
  const size_t SZ_QBF  = 2555904;    // 1664x768 bf16 (reused as final-GEMM scratch)
  const size_t SZ_KBF  = 1579008;    // 1028x768 bf16
  const size_t SZ_MID  = 13684736;   // 1028x6656 bf16 (later: c_buf + Tbuf)
  const size_t SZ_MM   = 1703936;    // 104x64x64 fp32
  const size_t SZ_WB   = 26624;      // 104x64 fp32
  const size_t SZ_MIDI = 13684736;   // (B,G,257,64) bf16
  const size_t SZ_PIM  = 427648;     // (B,G,257) fp32
  const size_t SZ_ABF  = 5271552;    // (B*H,416,264) bf16 (later: opbf)
  const size_t SZ_A2   = 5271552;    // (B*G,24,264) bf16
  const size_t SZ_SSH  = 39936;      // (B*H,416) fp32
  const size_t REQUIRED = SZ_FLAG + SZ_QBF + SZ_KBF + SZ_MID + SZ_MM + SZ_WB +
                          SZ_MIDI + SZ_PIM + SZ_ABF + SZ_A2 + SZ_SSH;  // 44,245,888

  if (ws_size < REQUIRED) {  // diagnostic: report ws_size in MB via output
    fill_k<<<(out_size + 255) / 256, 256, 0, stream>>>((u16*)d_out, (float)(ws_size >> 20), out_size);
    return;
  }

  char* p = (char*)d_ws;
  int*   dtf   = (int*)  p;                 p += SZ_FLAG;
  u16*   qbf   = (u16*)  p;                 p += SZ_QBF;
  u16*   kbf   = (u16*)  p;                 p += SZ_KBF;
  char*  midrg = p;                         p += SZ_MID;
  float* Mmat  = (float*)p;                 p += SZ_MM;
  float* wbar  = (float*)p;                 p += SZ_WB;
  u16*   midi  = (u16*)  p;                 p += SZ_MIDI;
  float* pim   = (float*)p;                 p += SZ_PIM;
  char*  abfrg = p;                         p += SZ_ABF;
  u16*   A2bf  = (u16*)  p;                 p += SZ_A2;
  float* s_sh  = (float*)p;                 p += SZ_SSH;

  u16*   midbf = (u16*)midrg;               // live: mid GEMM .. stats_k
  float* c_buf = (float*)midrg;             // live: c GEMM .. out_core
  float* Tbuf  = (float*)(midrg + 5111808); // live: T GEMM .. out_core
  u16*   Abf   = (u16*)abfrg;               // live: attn_k .. c GEMM
  u16*   opbf  = (u16*)abfrg;               // live: out_core .. final GEMM

  probe_k<<<1, 256, 0, stream>>>((const u32*)x, dtf);

  // q = LN(x @ Wq)
  launch_gemm(x, Wq, nullptr, qbf, 1, 1664, 768, 768, 768, 768, 768,
              0, 0, 0, 1, 0, 1, 0, 1.f, dtf, 1, 1, stream);
  ln_rows<<<1664, 256, 0, stream>>>(qbf, gq, bq, qbf, 768, dtf, 0);
  // k = LN(ctx @ Wk)
  launch_gemm(ctx, Wk, nullptr, kbf, 1, 1028, 768, 768, 768, 768, 768,
              0, 0, 0, 1, 0, 1, 0, 1.f, dtf, 1, 1, stream);
  ln_rows<<<1028, 256, 0, stream>>>(kbf, gk, bk, kbf, 768, dtf, 0);
  // mid = LN(ctx @ Wv)
  launch_gemm(ctx, Wv, nullptr, midbf, 1, 1028, 6656, 768, 768, 6656, 6656,
              0, 0, 0, 1, 0, 1, 0, 1.f, dtf, 1, 1, stream);
  ln_rows<<<1028, 256, 0, stream>>>(midbf, gv1, bv1, midbf, 6656, dtf, 0);
  // Gram: M[g] = Wconv[g] @ Wconv[g]^T / 768
  launch_gemm(Wcv, Wcv, Mmat, nullptr, 0, 64, 64, 768, 768, 768, 64,
              49152, 49152, 0, 1, 4096, 104, 1, 1.f / 768.f, dtf, 1, 1, stream);
  wbar_k<<<104, 256, 0, stream>>>(Wcv, wbar, dtf);
  stats_k<<<dim3(104, 17), 256, 0, stream>>>(midbf, Mmat, wbar, midi, pim);
  attn_k<<<dim3(24, 13), 256, 0, stream>>>(qbf, kbf, pim, Abf, A2bf, s_sh);
  // c = A @ ctx_head   (z = b*6+h)
  launch_gemm(Abf, ctx, c_buf, nullptr, 0, 416, 128, 257, 264, 768, 128,
              109824, 197376, 128, 6, 53248, 24, 0, 1.f, dtf, 0, 1, stream);
  // T = A2 @ midi      (z = b*104+g)
  launch_gemm(A2bf, midi, Tbuf, nullptr, 0, 24, 64, 257, 264, 64, 64,
              6336, 16448, 0, 1, 1536, 416, 0, 1.f, dtf, 0, 0, stream);
  out_core<<<1664, 256, 0, stream>>>(Tbuf, s_sh, c_buf, Wcv, gv2, bv2, opbf, dtf);
  // out = LN(out_pre @ Wo): GEMM -> qbf scratch (bf16), LN -> d_out (flag dtype)
  launch_gemm(opbf, Wo, nullptr, qbf, 1, 1664, 768, 768, 768, 768, 768,
              0, 0, 0, 1, 0, 1, 0, 1.f, dtf, 0, 1, stream);
  ln_rows<<<1664, 256, 0, stream>>>(qbf, go, bo, d_out, 768, dtf, 1);
}

// Round 6
// 540.609 us; speedup vs baseline: 1.6298x; 1.6298x over previous
//
#include <hip/hip_runtime.h>

// SubjBasisGenerator fused pipeline. B=4 NQ=416 NC=257 D=768 H=6 DH=128 G=104 R=4 LORA=64
// R6: attn_k (375us, VGPR-spill-bound, 7% occupancy) replaced by MFMA sim-GEMM
// + thin softmax kernel. out_core replaced by batched O-GEMM + coalesced combine.
// GEMM gains A-side batch decomposition and N-bound guards (N=257 tiles).
//
// Algebra: the grouped-conv+LN v-path decomposes exactly (no (B,G,NC,768) tensor):
//   sum_j A_j v_j = gv2*( (sum_j A_j inv_j mid_j)@Wconv[g] - sum_j A_j inv_j mu_j )
//                   + bv2 + (A @ ctx)

typedef unsigned short u16;
typedef unsigned int   u32;
typedef __attribute__((ext_vector_type(4))) float f32x4;
typedef __attribute__((ext_vector_type(4))) u32   u32x4;
typedef __attribute__((ext_vector_type(8))) short bf16x8;

__device__ __forceinline__ float bf2f(u16 v) { return __uint_as_float(((u32)v) << 16); }
__device__ __forceinline__ u16 f2bf(float f) {
  u32 u = __float_as_uint(f);
  u32 r = u + 0x7fffu + ((u >> 16) & 1u);  // RNE
  return (u16)(r >> 16);
}
__device__ __forceinline__ float gld(const void* p, long idx, int f32) {
  return f32 ? ((const float*)p)[idx] : bf2f(((const u16*)p)[idx]);
}

// ------------------------------------------------------------ dtype probe ---
__global__ __launch_bounds__(256) void probe_k(const u32* __restrict__ xw, int* __restrict__ flag) {
  int tid = threadIdx.x, c = 0;
  for (int i = tid; i < 4096; i += 256) {
    u16 lo = (u16)(xw[i] & 0xffffu);
    float a = fabsf(bf2f(lo));
    if (lo == 0 || (a >= 1e-3f && a <= 32.f)) ++c;
  }
#pragma unroll
  for (int o = 32; o; o >>= 1) c += __shfl_xor(c, o, 64);
  __shared__ int r[4];
  if ((tid & 63) == 0) r[tid >> 6] = c;
  __syncthreads();
  if (tid == 0) flag[0] = (r[0] + r[1] + r[2] + r[3] >= 2048) ? 0 : 1;  // 1 = fp32
}

// ------------------------------------------------------------ diag fill -----
__global__ __launch_bounds__(256) void fill_k(u16* p, float v, int n) {
  int i = blockIdx.x * 256 + threadIdx.x;
  if (i < n) p[i] = f2bf(v);
}

// ---------------------------------------------------------------- GEMM ------
// C = alpha*(A@B) (or A@B^T if btrans). aSel/bSel=1: operand follows dtype flag;
// 0: always-bf16 internal. Batch: zg = blockIdx.z + zoff;
//   aoff=(zg/adiv)*sAo+(zg%adiv)*sAi; boff=(zg/bdiv)*sBo+(zg%bdiv)*sBi;
//   C += blockIdx.z * sC.
// N-bounds guarded (btrans B rows and C writes). 64x64 tile, BK=32, 4 waves,
// 2x2 mfma_f32_16x16x32_bf16 per wave.
#define LDS_S 40

__global__ __launch_bounds__(256) void gemm_bf16(
    const void* __restrict__ A, const void* __restrict__ B,
    float* __restrict__ Cf, u16* __restrict__ Cb, int obf,
    int M, int N, int K, int lda, int ldb, int ldc,
    long sAo, long sAi, int adiv, long sBo, long sBi, int bdiv,
    long sC, int zoff, int btrans, float alpha,
    const int* __restrict__ dtf, int aSel, int bSel)
{
  const int f = dtf[0];
  const int af32 = aSel & f, bf32 = bSel & f;
  const int zl = blockIdx.z, zg = zl + zoff;
  const long aoff = (long)(zg / adiv) * sAo + (long)(zg % adiv) * sAi;
  const long boff = (long)(zg / bdiv) * sBo + (long)(zg % bdiv) * sBi;
  const u16*   A16 = (const u16*)A + aoff;
  const float* A32 = (const float*)A + aoff;
  const u16*   B16 = (const u16*)B + boff;
  const float* B32 = (const float*)B + boff;

  __shared__ __attribute__((aligned(16))) u16 As[64 * LDS_S];
  __shared__ __attribute__((aligned(16))) u16 Bs[64 * LDS_S];

  const int tid = threadIdx.x;
  const int lane = tid & 63, wave = tid >> 6;
  const int m0 = blockIdx.x * 64, n0 = blockIdx.y * 64;
  const int wm = (wave >> 1) * 32, wn = (wave & 1) * 32;
  const int fm = lane & 15, fq = lane >> 4;

  const int ar = tid >> 2, ak = (tid & 3) * 8;   // A staging: row, k-offset
  const int bk = tid >> 3, bn = (tid & 7) * 8;   // B staging (non-trans path)

  f32x4 acc[2][2];
  const f32x4 zero4 = {0.f, 0.f, 0.f, 0.f};
#pragma unroll
  for (int a_ = 0; a_ < 2; ++a_)
#pragma unroll
    for (int b_ = 0; b_ < 2; ++b_) acc[a_][b_] = zero4;

  for (int k0 = 0; k0 < K; k0 += 32) {
    // ---- stage A tile (64 x 32) ----
    {
      int gm = m0 + ar, gk = k0 + ak;
      long idx = (long)gm * lda + gk;
      if (gm < M && gk + 8 <= K) {
        if (af32) {
          f32x4 u = *(const f32x4*)(A32 + idx), v = *(const f32x4*)(A32 + idx + 4);
          u32x4 q = { (u32)f2bf(u.x) | ((u32)f2bf(u.y) << 16),
                      (u32)f2bf(u.z) | ((u32)f2bf(u.w) << 16),
                      (u32)f2bf(v.x) | ((u32)f2bf(v.y) << 16),
                      (u32)f2bf(v.z) | ((u32)f2bf(v.w) << 16) };
          *(u32x4*)&As[ar * LDS_S + ak] = q;
        } else {
          *(u32x4*)&As[ar * LDS_S + ak] = *(const u32x4*)(A16 + idx);
        }
      } else {
#pragma unroll
        for (int e = 0; e < 8; ++e) {
          u16 v = 0;
          if (gm < M && gk + e < K) v = f2bf(gld(A, aoff + idx + e, af32));
          As[ar * LDS_S + ak + e] = v;
        }
      }
    }
    // ---- stage B tile as Bs[n][k] (64 x 32) ----
    if (btrans) {
      int gn = n0 + ar, gk = k0 + ak;
      long idx = (long)gn * ldb + gk;
      if (gn < N && gk + 8 <= K) {
        if (bf32) {
          f32x4 u = *(const f32x4*)(B32 + idx), v = *(const f32x4*)(B32 + idx + 4);
          u32x4 q = { (u32)f2bf(u.x) | ((u32)f2bf(u.y) << 16),
                      (u32)f2bf(u.z) | ((u32)f2bf(u.w) << 16),
                      (u32)f2bf(v.x) | ((u32)f2bf(v.y) << 16),
                      (u32)f2bf(v.z) | ((u32)f2bf(v.w) << 16) };
          *(u32x4*)&Bs[ar * LDS_S + ak] = q;
        } else {
          *(u32x4*)&Bs[ar * LDS_S + ak] = *(const u32x4*)(B16 + idx);
        }
      } else {
#pragma unroll
        for (int e = 0; e < 8; ++e) {
          u16 v = 0;
          if (gn < N && gk + e < K) v = f2bf(gld(B, boff + idx + e, bf32));
          Bs[ar * LDS_S + ak + e] = v;
        }
      }
    } else {
      int gk = k0 + bk;
      long idx = (long)gk * ldb + n0 + bn;
      u16 tmp[8];
      if (gk < K) {
        if (bf32) {
          f32x4 u = *(const f32x4*)(B32 + idx), v = *(const f32x4*)(B32 + idx + 4);
          tmp[0] = f2bf(u.x); tmp[1] = f2bf(u.y); tmp[2] = f2bf(u.z); tmp[3] = f2bf(u.w);
          tmp[4] = f2bf(v.x); tmp[5] = f2bf(v.y); tmp[6] = f2bf(v.z); tmp[7] = f2bf(v.w);
        } else {
          u32x4 v = *(const u32x4*)(B16 + idx);
          tmp[0] = (u16)(v.x & 0xffff); tmp[1] = (u16)(v.x >> 16);
          tmp[2] = (u16)(v.y & 0xffff); tmp[3] = (u16)(v.y >> 16);
          tmp[4] = (u16)(v.z & 0xffff); tmp[5] = (u16)(v.z >> 16);
          tmp[6] = (u16)(v.w & 0xffff); tmp[7] = (u16)(v.w >> 16);
        }
      } else {
#pragma unroll
        for (int e = 0; e < 8; ++e) tmp[e] = 0;
      }
      int rot = tid & 7;  // spread LDS bank writes
#pragma unroll
      for (int e = 0; e < 8; ++e) {
        int ee = (e + rot) & 7;
        Bs[(bn + ee) * LDS_S + bk] = tmp[ee];
      }
    }
    __syncthreads();
    {
      bf16x8 fa[2], fb[2];
      fa[0] = *(const bf16x8*)&As[(wm +      fm) * LDS_S + fq * 8];
      fa[1] = *(const bf16x8*)&As[(wm + 16 + fm) * LDS_S + fq * 8];
      fb[0] = *(const bf16x8*)&Bs[(wn +      fm) * LDS_S + fq * 8];
      fb[1] = *(const bf16x8*)&Bs[(wn + 16 + fm) * LDS_S + fq * 8];
#pragma unroll
      for (int mt = 0; mt < 2; ++mt)
#pragma unroll
        for (int nt = 0; nt < 2; ++nt)
          acc[mt][nt] = __builtin_amdgcn_mfma_f32_16x16x32_bf16(fa[mt], fb[nt], acc[mt][nt], 0, 0, 0);
    }
    __syncthreads();
  }
  // epilogue: C/D layout col=lane&15, row=(lane>>4)*4+reg (m89-verified)
#pragma unroll
  for (int mt = 0; mt < 2; ++mt)
#pragma unroll
    for (int nt = 0; nt < 2; ++nt)
#pragma unroll
      for (int rr = 0; rr < 4; ++rr) {
        int gm = m0 + wm + mt * 16 + fq * 4 + rr;
        int gn = n0 + wn + nt * 16 + fm;
        if (gm < M && gn < N) {
          float v = alpha * acc[mt][nt][rr];
          if (obf) Cb[(long)zl * sC + (long)gm * ldc + gn] = f2bf(v);
          else     Cf[(long)zl * sC + (long)gm * ldc + gn] = v;
        }
      }
}

// ------------------------------------------------------------- row LN -------
__global__ __launch_bounds__(256) void ln_rows(
    const u16* __restrict__ in, const void* __restrict__ g, const void* __restrict__ b,
    void* __restrict__ out, int N, const int* __restrict__ dtf, int isfinal)
{
  const int f = dtf[0];
  long row = blockIdx.x;
  const u16* ip = in + row * N;
  int tid = threadIdx.x, lane = tid & 63, wave = tid >> 6;
  float s1 = 0.f, s2 = 0.f;
  for (int c = tid; c < N; c += 256) { float v = bf2f(ip[c]); s1 += v; s2 += v * v; }
#pragma unroll
  for (int o = 32; o; o >>= 1) { s1 += __shfl_xor(s1, o, 64); s2 += __shfl_xor(s2, o, 64); }
  __shared__ float red[8];
  if (lane == 0) { red[wave] = s1; red[4 + wave] = s2; }
  __syncthreads();
  s1 = red[0] + red[1] + red[2] + red[3];
  s2 = red[4] + red[5] + red[6] + red[7];
  float mean = s1 / N;
  float var = s2 / N - mean * mean;
  float rstd = rsqrtf(fmaxf(var, 0.f) + 1e-5f);
  for (int c = tid; c < N; c += 256) {
    float val = (bf2f(ip[c]) - mean) * rstd * gld(g, c, f) + gld(b, c, f);
    if (isfinal && f) ((float*)out)[row * N + c] = val;
    else              ((u16*)out)[row * N + c] = f2bf(val);
  }
}

// ------------------------------------------------------------- wbar ---------
__global__ __launch_bounds__(256) void wbar_k(const void* __restrict__ Wconv,
                                              float* __restrict__ wbar,
                                              const int* __restrict__ dtf)
{
  const int f = dtf[0];
  int g = blockIdx.x;
  int lane = threadIdx.x & 63, wave = threadIdx.x >> 6;
  long base = (long)g * 49152;
  for (int l = wave * 16; l < wave * 16 + 16; ++l) {
    float s = 0.f;
    for (int c = lane; c < 768; c += 64) s += gld(Wconv, base + (long)l * 768 + c, f);
#pragma unroll
    for (int o = 32; o; o >>= 1) s += __shfl_xor(s, o, 64);
    if (lane == 0) wbar[g * 64 + l] = s * (1.f / 768.f);
  }
}

// ------------------------------------------------------------- stats --------
__global__ __launch_bounds__(256) void stats_k(
    const u16* __restrict__ midbf, const float* __restrict__ Mmat, const float* __restrict__ wbar,
    u16* __restrict__ midi, float* __restrict__ pim)
{
  int g = blockIdx.x;
  int row0 = blockIdx.y * 64;
  int tid = threadIdx.x, lane = tid & 63, wave = tid >> 6;
  __shared__ __attribute__((aligned(16))) float Ms[64 * 68];
  __shared__ __attribute__((aligned(16))) float mrow[4][64];
  __shared__ float wb[64];
  {
    int l1 = tid >> 2, c0 = (tid & 3) * 16;
    const float* src = Mmat + (long)g * 4096 + l1 * 64 + c0;
    float* dst = &Ms[l1 * 68 + c0];
#pragma unroll
    for (int e = 0; e < 16; e += 4) *(f32x4*)(dst + e) = *(const f32x4*)(src + e);
  }
  if (tid < 64) wb[tid] = wbar[g * 64 + tid];
  __syncthreads();
  for (int t = 0; t < 16; ++t) {
    int r = row0 + wave * 16 + t;            // flat (b*257+j) row
    bool valid = r < 1028;
    float m = valid ? bf2f(midbf[(long)r * 6656 + g * 64 + lane]) : 0.f;
    mrow[wave][lane] = m;
    __syncthreads();
    float rowdot = 0.f;
    const f32x4* Mr = (const f32x4*)&Ms[lane * 68];
    const f32x4* xr = (const f32x4*)&mrow[wave][0];
#pragma unroll
    for (int c = 0; c < 16; ++c) {
      f32x4 a = Mr[c], x = xr[c];
      rowdot = fmaf(a.x, x.x, rowdot); rowdot = fmaf(a.y, x.y, rowdot);
      rowdot = fmaf(a.z, x.z, rowdot); rowdot = fmaf(a.w, x.w, rowdot);
    }
    float mup = m * wb[lane];
    float q2p = m * rowdot;
#pragma unroll
    for (int o = 32; o; o >>= 1) { mup += __shfl_xor(mup, o, 64); q2p += __shfl_xor(q2p, o, 64); }
    float var = q2p - mup * mup;
    float inv = rsqrtf(fmaxf(var, 0.f) + 1e-5f);
    if (valid) {
      int bb = r / 257, j = r - bb * 257;
      long base = ((long)bb * 104 + g) * 257 + j;
      midi[base * 64 + lane] = f2bf(inv * m);
      if (lane == 0) pim[base] = inv * mup;
    }
    __syncthreads();
  }
}

// ------------------------------------------------------------- softmax ------
// grid (24, 104), 4 waves/block, 1 wave per query row. Reads sim fp32 rows
// (ldc 257), writes normalized probs bf16 to Abf[(b,h),i,:264] and
// A2bf[(b,g),h*4+rq,:264] (zero-padded), plus s_sh = sum_j p*pim.
__global__ __launch_bounds__(256) void softmax_k(
    const float* __restrict__ simf, const float* __restrict__ pim,
    u16* __restrict__ Abf, u16* __restrict__ A2bf, float* __restrict__ s_sh)
{
  int bh = blockIdx.x;
  int b = bh / 6, h = bh - b * 6;
  int tid = threadIdx.x, lane = tid & 63, wave = tid >> 6;
  int i = blockIdx.y * 4 + wave;
  int g = i % 104, rq = i / 104;
  const float* sp_ = simf + ((long)bh * 416 + i) * 257;
  float s[5];
#pragma unroll
  for (int jc = 0; jc < 5; ++jc) {
    int j = jc * 64 + lane;
    s[jc] = (j < 257) ? sp_[j] : -1e30f;
  }
  float mx = -1e30f;
#pragma unroll
  for (int jc = 0; jc < 5; ++jc) mx = fmaxf(mx, s[jc]);
#pragma unroll
  for (int o = 32; o; o >>= 1) mx = fmaxf(mx, __shfl_xor(mx, o, 64));
  float p[5], sum = 0.f, sp = 0.f;
  long pimb = ((long)b * 104 + g) * 257;
#pragma unroll
  for (int jc = 0; jc < 5; ++jc) {
    int j = jc * 64 + lane;
    float pv = 0.f;
    if (j < 257) { pv = __expf(s[jc] - mx); sp = fmaf(pv, pim[pimb + j], sp); }
    p[jc] = pv; sum += pv;
  }
#pragma unroll
  for (int o = 32; o; o >>= 1) { sum += __shfl_xor(sum, o, 64); sp += __shfl_xor(sp, o, 64); }
  float rs = 1.f / sum;
  long arow  = ((long)bh * 416 + i) * 264;
  long a2row = (((long)b * 104 + g) * 24 + h * 4 + rq) * 264;
#pragma unroll
  for (int jc = 0; jc < 5; ++jc) {
    int j = jc * 64 + lane;
    if (j < 257) { u16 pb = f2bf(p[jc] * rs); Abf[arow + j] = pb; A2bf[a2row + j] = pb; }
    else if (j < 264) { Abf[arow + j] = 0; A2bf[a2row + j] = 0; }
  }
  if (lane == 0) s_sh[(long)bh * 416 + i] = sp * rs;
}

// ------------------------------------------------------------- combine ------
// opbf[b,i,d] = gv2[d]*(O[(b,g),h*4+rq,d] - ssh[b,h,i]) + bv2[d] + c_buf[b,h,i,dh]
__global__ __launch_bounds__(256) void combine_k(
    const u16* __restrict__ O, const float* __restrict__ s_sh, const float* __restrict__ c_buf,
    const void* __restrict__ gv2, const void* __restrict__ bv2,
    u16* __restrict__ opbf, const int* __restrict__ dtf)
{
  const int f = dtf[0];
  int bi = blockIdx.x;
  int b = bi / 416, i = bi - b * 416;
  int g = i % 104, rq = i / 104;
  int tid = threadIdx.x;
  long obase = ((long)b * 104 + g) * 24 * 768;
#pragma unroll
  for (int it = 0; it < 3; ++it) {
    int d = tid + it * 256;
    int h = d >> 7, dh = d & 127;
    float o = bf2f(O[obase + (long)(h * 4 + rq) * 768 + d]);
    float ssh = s_sh[((long)b * 6 + h) * 416 + i];
    float val = gld(gv2, d, f) * (o - ssh) + gld(bv2, d, f)
              + c_buf[(((long)b * 6 + h) * 416 + i) * 128 + dh];
    opbf[((long)b * 416 + i) * 768 + d] = f2bf(val);
  }
}

// ---------------------------------------------------------------- host ------
static void launch_gemm(const void* A, const void* B, float* Cf, u16* Cb, int obf,
                        int M, int N, int K, int lda, int ldb, int ldc,
                        long sAo, long sAi, int adiv, long sBo, long sBi, int bdiv,
                        long sC, int zoff, int Z, int btrans, float alpha,
                        const int* dtf, int aSel, int bSel, hipStream_t st)
{
  dim3 grid((M + 63) / 64, (N + 63) / 64, Z);
  gemm_bf16<<<grid, dim3(256), 0, st>>>(A, B, Cf, Cb, obf, M, N, K, lda, ldb, ldc,
                                        sAo, sAi, adiv, sBo, sBi, bdiv,
                                        sC, zoff, btrans, alpha, dtf, aSel, bSel);
}

extern "C" void kernel_launch(void* const* d_in, const int* in_sizes, int n_in,
                              void* d_out, int out_size, void* d_ws, size_t ws_size,
                              hipStream_t stream)
{
  (void)in_sizes; (void)n_in;
  const void* x   = d_in[0];
  const void* ctx = d_in[1];
  const void* Wq  = d_in[2];
  const void* gq  = d_in[3];
  const void* bq  = d_in[4];
  const void* Wk  = d_in[5];
  const void* gk  = d_in[6];
  const void* bk  = d_in[7];
  const void* Wv  = d_in[8];
  const void* gv1 = d_in[9];
  const void* bv1 = d_in[10];
  const void* Wcv = d_in[11];
  const void* gv2 = d_in[12];
  const void* bv2 = d_in[13];
  const void* Wo  = d_in[14];
  const void* go  = d_in[15];
  const void* bo  = d_in[16];

  // -------- workspace layout (same REQUIRED as R5 — known-good) --------
  const size_t SZ_FLAG = 256;
  const size_t SZ_QBF  = 2555904;    // 1664x768 bf16 (reused as final-GEMM scratch)
  const size_t SZ_KBF  = 1579008;    // 1028x768 bf16
  const size_t SZ_MID  = 13684736;   // midbf; later: simf (10.27MB) -> c_buf+Tb16
  const size_t SZ_MM   = 1703936;    // Mmat; later (+WB+MIDI+PIM): O bf16 15.34MB
  const size_t SZ_WB   = 26624;
  const size_t SZ_MIDI = 13684736;
  const size_t SZ_PIM  = 427648;
  const size_t SZ_ABF  = 5271552;    // Abf; later: opbf
  const size_t SZ_A2   = 5271552;
  const size_t SZ_SSH  = 39936;
  const size_t REQUIRED = SZ_FLAG + SZ_QBF + SZ_KBF + SZ_MID + SZ_MM + SZ_WB +
                          SZ_MIDI + SZ_PIM + SZ_ABF + SZ_A2 + SZ_SSH;  // 44,245,888

  if (ws_size < REQUIRED) {
    fill_k<<<(out_size + 255) / 256, 256, 0, stream>>>((u16*)d_out, (float)(ws_size >> 20), out_size);
    return;
  }

  char* p = (char*)d_ws;
  int*   dtf   = (int*)  p;                 p += SZ_FLAG;
  u16*   qbf   = (u16*)  p;                 p += SZ_QBF;
  u16*   kbf   = (u16*)  p;                 p += SZ_KBF;
  char*  midrg = p;                         p += SZ_MID;
  char*  mmrg  = p;                         p += SZ_MM;
  float* wbar  = (float*)p;                 p += SZ_WB;
  u16*   midi  = (u16*)  p;                 p += SZ_MIDI;
  float* pim   = (float*)p;                 p += SZ_PIM;
  char*  abfrg = p;                         p += SZ_ABF;
  u16*   A2bf  = (u16*)  p;                 p += SZ_A2;
  float* s_sh  = (float*)p;                 p += SZ_SSH;

  u16*   midbf = (u16*)midrg;               // live: mid GEMM .. stats_k
  float* simf  = (float*)midrg;             // live: sim GEMM .. softmax (10.27MB)
  float* c_buf = (float*)midrg;             // live: c GEMM .. combine (5.11MB)
  u16*   Tb16  = (u16*)(midrg + 5111808);   // live: T GEMM .. O GEMM (1.28MB)
  float* Mmat  = (float*)mmrg;              // live: gram .. stats_k
  u16*   Obf   = (u16*)mmrg;                // live: O GEMM .. combine (15.34MB over MM+WB+MIDI+PIM)
  u16*   Abf   = (u16*)abfrg;               // live: softmax .. c GEMM
  u16*   opbf  = (u16*)abfrg;               // live: combine .. final GEMM

  probe_k<<<1, 256, 0, stream>>>((const u32*)x, dtf);

  // q = LN(x @ Wq)
  launch_gemm(x, Wq, nullptr, qbf, 1, 1664, 768, 768, 768, 768, 768,
              0, 0, 1, 0, 0, 1, 0, 0, 1, 0, 1.f, dtf, 1, 1, stream);
  ln_rows<<<1664, 256, 0, stream>>>(qbf, gq, bq, qbf, 768, dtf, 0);
  // k = LN(ctx @ Wk)
  launch_gemm(ctx, Wk, nullptr, kbf, 1, 1028, 768, 768, 768, 768, 768,
              0, 0, 1, 0, 0, 1, 0, 0, 1, 0, 1.f, dtf, 1, 1, stream);
  ln_rows<<<1028, 256, 0, stream>>>(kbf, gk, bk, kbf, 768, dtf, 0);
  // mid = LN(ctx @ Wv)
  launch_gemm(ctx, Wv, nullptr, midbf, 1, 1028, 6656, 768, 768, 6656, 6656,
              0, 0, 1, 0, 0, 1, 0, 0, 1, 0, 1.f, dtf, 1, 1, stream);
  ln_rows<<<1028, 256, 0, stream>>>(midbf, gv1, bv1, midbf, 6656, dtf, 0);
  // Gram: M[g] = Wconv[g] @ Wconv[g]^T / 768   (z=104)
  launch_gemm(Wcv, Wcv, Mmat, nullptr, 0, 64, 64, 768, 768, 768, 64,
              49152, 0, 1, 49152, 0, 1, 4096, 0, 104, 1, 1.f / 768.f, dtf, 1, 1, stream);
  wbar_k<<<104, 256, 0, stream>>>(Wcv, wbar, dtf);
  stats_k<<<dim3(104, 17), 256, 0, stream>>>(midbf, Mmat, wbar, midi, pim);
  // sim = scale^2 * q @ k^T   (z = b*6+h, btrans, fp32 out, ldc=257)
  launch_gemm(qbf, kbf, simf, nullptr, 0, 416, 257, 128, 768, 768, 257,
              319488, 128, 6, 197376, 128, 6, 106912, 0, 24, 1,
              0.08838834764831845f, dtf, 0, 0, stream);
  softmax_k<<<dim3(24, 104), 256, 0, stream>>>(simf, pim, Abf, A2bf, s_sh);
  // c = A @ ctx_head   (z = b*6+h)
  launch_gemm(Abf, ctx, c_buf, nullptr, 0, 416, 128, 257, 264, 768, 128,
              109824, 0, 1, 197376, 128, 6, 53248, 0, 24, 0, 1.f, dtf, 0, 1, stream);
  // T = A2 @ midi      (z = b*104+g, bf16 out)
  launch_gemm(A2bf, midi, nullptr, Tb16, 1, 24, 64, 257, 264, 64, 64,
              6336, 0, 1, 16448, 0, 1, 1536, 0, 416, 0, 1.f, dtf, 0, 0, stream);
  // O = T @ Wconv[g]   (z = b*104+g, bf16 out over dead Mmat..pim span)
  launch_gemm(Tb16, Wcv, nullptr, Obf, 1, 24, 768, 64, 64, 768, 768,
              1536, 0, 1, 0, 49152, 104, 18432, 0, 416, 0, 1.f, dtf, 0, 1, stream);
  combine_k<<<1664, 256, 0, stream>>>(Obf, s_sh, c_buf, gv2, bv2, opbf, dtf);
  // out = LN(out_pre @ Wo): GEMM -> qbf scratch, LN -> d_out (flag dtype)
  launch_gemm(opbf, Wo, nullptr, qbf, 1, 1664, 768, 768, 768, 768, 768,
              0, 0, 1, 0, 0, 1, 0, 0, 1, 0, 1.f, dtf, 0, 1, stream);
  ln_rows<<<1664, 256, 0, stream>>>(qbf, go, bo, d_out, 768, dtf, 1);
}

// Round 7
// 474.888 us; speedup vs baseline: 1.8553x; 1.1384x over previous
//
#include <hip/hip_runtime.h>

// SubjBasisGenerator fused pipeline. B=4 NQ=416 NC=257 D=768 H=6 DH=128 G=104 R=4 LORA=64
// R7: all large GEMMs now consume pre-converted bf16 operands (convb_k) with
// weights pre-transposed to N-major (transb_k) -> btrans path, 16B vector
// staging both sides, no per-tile f2bf, no scatter LDS writes.
// (R6 mid GEMM: 93us, MfmaUtil 4.6%, VALUBusy 56%, 4.5M LDS bank conflicts.)
//
// Algebra: the grouped-conv+LN v-path decomposes exactly (no (B,G,NC,768) tensor):
//   sum_j A_j v_j = gv2*( (sum_j A_j inv_j mid_j)@Wconv[g] - sum_j A_j inv_j mu_j )
//                   + bv2 + (A @ ctx)

typedef unsigned short u16;
typedef unsigned int   u32;
typedef __attribute__((ext_vector_type(4))) float f32x4;
typedef __attribute__((ext_vector_type(4))) u32   u32x4;
typedef __attribute__((ext_vector_type(8))) short bf16x8;

__device__ __forceinline__ float bf2f(u16 v) { return __uint_as_float(((u32)v) << 16); }
__device__ __forceinline__ u16 f2bf(float f) {
  u32 u = __float_as_uint(f);
  u32 r = u + 0x7fffu + ((u >> 16) & 1u);  // RNE
  return (u16)(r >> 16);
}
__device__ __forceinline__ float gld(const void* p, long idx, int f32) {
  return f32 ? ((const float*)p)[idx] : bf2f(((const u16*)p)[idx]);
}

// ------------------------------------------------------------ dtype probe ---
__global__ __launch_bounds__(256) void probe_k(const u32* __restrict__ xw, int* __restrict__ flag) {
  int tid = threadIdx.x, c = 0;
  for (int i = tid; i < 4096; i += 256) {
    u16 lo = (u16)(xw[i] & 0xffffu);
    float a = fabsf(bf2f(lo));
    if (lo == 0 || (a >= 1e-3f && a <= 32.f)) ++c;
  }
#pragma unroll
  for (int o = 32; o; o >>= 1) c += __shfl_xor(c, o, 64);
  __shared__ int r[4];
  if ((tid & 63) == 0) r[tid >> 6] = c;
  __syncthreads();
  if (tid == 0) flag[0] = (r[0] + r[1] + r[2] + r[3] >= 2048) ? 0 : 1;  // 1 = fp32
}

// ------------------------------------------------------------ diag fill -----
__global__ __launch_bounds__(256) void fill_k(u16* p, float v, int n) {
  int i = blockIdx.x * 256 + threadIdx.x;
  if (i < n) p[i] = f2bf(v);
}

// ------------------------------------------------------- ext -> bf16 copy ---
__global__ __launch_bounds__(256) void convb_k(const void* __restrict__ in, u16* __restrict__ out,
                                               int n, const int* __restrict__ dtf) {
  const int f = dtf[0];
  int i = (blockIdx.x * 256 + threadIdx.x) * 8;
  if (i + 8 <= n) {
    if (f) {
      const float* ip = (const float*)in + i;
      f32x4 a = *(const f32x4*)ip, b = *(const f32x4*)(ip + 4);
      u32x4 q = { (u32)f2bf(a.x) | ((u32)f2bf(a.y) << 16),
                  (u32)f2bf(a.z) | ((u32)f2bf(a.w) << 16),
                  (u32)f2bf(b.x) | ((u32)f2bf(b.y) << 16),
                  (u32)f2bf(b.z) | ((u32)f2bf(b.w) << 16) };
      *(u32x4*)(out + i) = q;
    } else {
      *(u32x4*)(out + i) = *(const u32x4*)((const u16*)in + i);
    }
  } else {
    for (; i < n; ++i) out[i] = f2bf(gld(in, i, f));
  }
}

// ------------------------------------- ext [K,N] -> bf16 [N,K] transpose ----
__global__ __launch_bounds__(256) void transb_k(const void* __restrict__ in, u16* __restrict__ out,
                                                int K, int N, const int* __restrict__ dtf) {
  const int f = dtf[0];
  __shared__ float s[32][33];
  int n0 = blockIdx.x * 32, k0 = blockIdx.y * 32;
  int tx = threadIdx.x & 31, ty = threadIdx.x >> 5;  // 32 x 8
#pragma unroll
  for (int i = 0; i < 32; i += 8) {
    int k = k0 + ty + i, n = n0 + tx;
    float v = 0.f;
    if (k < K && n < N) v = gld(in, (long)k * N + n, f);
    s[ty + i][tx] = v;
  }
  __syncthreads();
#pragma unroll
  for (int i = 0; i < 32; i += 8) {
    int n = n0 + ty + i, k = k0 + tx;
    if (n < N && k < K) out[(long)n * K + k] = f2bf(s[tx][ty + i]);
  }
}

// ---------------------------------------------------------------- GEMM ------
// C = alpha*(A@B) (or A@B^T if btrans). aSel/bSel=1: operand follows dtype flag;
// 0: always-bf16 internal. Batch: zg = blockIdx.z + zoff;
//   aoff=(zg/adiv)*sAo+(zg%adiv)*sAi; boff=(zg/bdiv)*sBo+(zg%bdiv)*sBi;
//   C += blockIdx.z * sC. N-bounds guarded. 64x64 tile, BK=32, 4 waves,
// 2x2 mfma_f32_16x16x32_bf16 per wave.
#define LDS_S 40

__global__ __launch_bounds__(256) void gemm_bf16(
    const void* __restrict__ A, const void* __restrict__ B,
    float* __restrict__ Cf, u16* __restrict__ Cb, int obf,
    int M, int N, int K, int lda, int ldb, int ldc,
    long sAo, long sAi, int adiv, long sBo, long sBi, int bdiv,
    long sC, int zoff, int btrans, float alpha,
    const int* __restrict__ dtf, int aSel, int bSel)
{
  const int f = dtf[0];
  const int af32 = aSel & f, bf32 = bSel & f;
  const int zl = blockIdx.z, zg = zl + zoff;
  const long aoff = (long)(zg / adiv) * sAo + (long)(zg % adiv) * sAi;
  const long boff = (long)(zg / bdiv) * sBo + (long)(zg % bdiv) * sBi;
  const u16*   A16 = (const u16*)A + aoff;
  const float* A32 = (const float*)A + aoff;
  const u16*   B16 = (const u16*)B + boff;
  const float* B32 = (const float*)B + boff;

  __shared__ __attribute__((aligned(16))) u16 As[64 * LDS_S];
  __shared__ __attribute__((aligned(16))) u16 Bs[64 * LDS_S];

  const int tid = threadIdx.x;
  const int lane = tid & 63, wave = tid >> 6;
  const int m0 = blockIdx.x * 64, n0 = blockIdx.y * 64;
  const int wm = (wave >> 1) * 32, wn = (wave & 1) * 32;
  const int fm = lane & 15, fq = lane >> 4;

  const int ar = tid >> 2, ak = (tid & 3) * 8;   // A staging: row, k-offset
  const int bk = tid >> 3, bn = (tid & 7) * 8;   // B staging (non-trans path)

  f32x4 acc[2][2];
  const f32x4 zero4 = {0.f, 0.f, 0.f, 0.f};
#pragma unroll
  for (int a_ = 0; a_ < 2; ++a_)
#pragma unroll
    for (int b_ = 0; b_ < 2; ++b_) acc[a_][b_] = zero4;

  for (int k0 = 0; k0 < K; k0 += 32) {
    // ---- stage A tile (64 x 32) ----
    {
      int gm = m0 + ar, gk = k0 + ak;
      long idx = (long)gm * lda + gk;
      if (gm < M && gk + 8 <= K) {
        if (af32) {
          f32x4 u = *(const f32x4*)(A32 + idx), v = *(const f32x4*)(A32 + idx + 4);
          u32x4 q = { (u32)f2bf(u.x) | ((u32)f2bf(u.y) << 16),
                      (u32)f2bf(u.z) | ((u32)f2bf(u.w) << 16),
                      (u32)f2bf(v.x) | ((u32)f2bf(v.y) << 16),
                      (u32)f2bf(v.z) | ((u32)f2bf(v.w) << 16) };
          *(u32x4*)&As[ar * LDS_S + ak] = q;
        } else {
          *(u32x4*)&As[ar * LDS_S + ak] = *(const u32x4*)(A16 + idx);
        }
      } else {
#pragma unroll
        for (int e = 0; e < 8; ++e) {
          u16 v = 0;
          if (gm < M && gk + e < K) v = f2bf(gld(A, aoff + idx + e, af32));
          As[ar * LDS_S + ak + e] = v;
        }
      }
    }
    // ---- stage B tile as Bs[n][k] (64 x 32) ----
    if (btrans) {
      int gn = n0 + ar, gk = k0 + ak;
      long idx = (long)gn * ldb + gk;
      if (gn < N && gk + 8 <= K) {
        if (bf32) {
          f32x4 u = *(const f32x4*)(B32 + idx), v = *(const f32x4*)(B32 + idx + 4);
          u32x4 q = { (u32)f2bf(u.x) | ((u32)f2bf(u.y) << 16),
                      (u32)f2bf(u.z) | ((u32)f2bf(u.w) << 16),
                      (u32)f2bf(v.x) | ((u32)f2bf(v.y) << 16),
                      (u32)f2bf(v.z) | ((u32)f2bf(v.w) << 16) };
          *(u32x4*)&Bs[ar * LDS_S + ak] = q;
        } else {
          *(u32x4*)&Bs[ar * LDS_S + ak] = *(const u32x4*)(B16 + idx);
        }
      } else {
#pragma unroll
        for (int e = 0; e < 8; ++e) {
          u16 v = 0;
          if (gn < N && gk + e < K) v = f2bf(gld(B, boff + idx + e, bf32));
          Bs[ar * LDS_S + ak + e] = v;
        }
      }
    } else {
      int gk = k0 + bk;
      long idx = (long)gk * ldb + n0 + bn;
      u16 tmp[8];
      if (gk < K) {
        if (bf32) {
          f32x4 u = *(const f32x4*)(B32 + idx), v = *(const f32x4*)(B32 + idx + 4);
          tmp[0] = f2bf(u.x); tmp[1] = f2bf(u.y); tmp[2] = f2bf(u.z); tmp[3] = f2bf(u.w);
          tmp[4] = f2bf(v.x); tmp[5] = f2bf(v.y); tmp[6] = f2bf(v.z); tmp[7] = f2bf(v.w);
        } else {
          u32x4 v = *(const u32x4*)(B16 + idx);
          tmp[0] = (u16)(v.x & 0xffff); tmp[1] = (u16)(v.x >> 16);
          tmp[2] = (u16)(v.y & 0xffff); tmp[3] = (u16)(v.y >> 16);
          tmp[4] = (u16)(v.z & 0xffff); tmp[5] = (u16)(v.z >> 16);
          tmp[6] = (u16)(v.w & 0xffff); tmp[7] = (u16)(v.w >> 16);
        }
      } else {
#pragma unroll
        for (int e = 0; e < 8; ++e) tmp[e] = 0;
      }
      int rot = tid & 7;  // spread LDS bank writes
#pragma unroll
      for (int e = 0; e < 8; ++e) {
        int ee = (e + rot) & 7;
        Bs[(bn + ee) * LDS_S + bk] = tmp[ee];
      }
    }
    __syncthreads();
    {
      bf16x8 fa[2], fb[2];
      fa[0] = *(const bf16x8*)&As[(wm +      fm) * LDS_S + fq * 8];
      fa[1] = *(const bf16x8*)&As[(wm + 16 + fm) * LDS_S + fq * 8];
      fb[0] = *(const bf16x8*)&Bs[(wn +      fm) * LDS_S + fq * 8];
      fb[1] = *(const bf16x8*)&Bs[(wn + 16 + fm) * LDS_S + fq * 8];
#pragma unroll
      for (int mt = 0; mt < 2; ++mt)
#pragma unroll
        for (int nt = 0; nt < 2; ++nt)
          acc[mt][nt] = __builtin_amdgcn_mfma_f32_16x16x32_bf16(fa[mt], fb[nt], acc[mt][nt], 0, 0, 0);
    }
    __syncthreads();
  }
  // epilogue: C/D layout col=lane&15, row=(lane>>4)*4+reg (m89-verified)
#pragma unroll
  for (int mt = 0; mt < 2; ++mt)
#pragma unroll
    for (int nt = 0; nt < 2; ++nt)
#pragma unroll
      for (int rr = 0; rr < 4; ++rr) {
        int gm = m0 + wm + mt * 16 + fq * 4 + rr;
        int gn = n0 + wn + nt * 16 + fm;
        if (gm < M && gn < N) {
          float v = alpha * acc[mt][nt][rr];
          if (obf) Cb[(long)zl * sC + (long)gm * ldc + gn] = f2bf(v);
          else     Cf[(long)zl * sC + (long)gm * ldc + gn] = v;
        }
      }
}

// ------------------------------------------------------------- row LN -------
__global__ __launch_bounds__(256) void ln_rows(
    const u16* __restrict__ in, const void* __restrict__ g, const void* __restrict__ b,
    void* __restrict__ out, int N, const int* __restrict__ dtf, int isfinal)
{
  const int f = dtf[0];
  long row = blockIdx.x;
  const u16* ip = in + row * N;
  int tid = threadIdx.x, lane = tid & 63, wave = tid >> 6;
  float s1 = 0.f, s2 = 0.f;
  for (int c = tid; c < N; c += 256) { float v = bf2f(ip[c]); s1 += v; s2 += v * v; }
#pragma unroll
  for (int o = 32; o; o >>= 1) { s1 += __shfl_xor(s1, o, 64); s2 += __shfl_xor(s2, o, 64); }
  __shared__ float red[8];
  if (lane == 0) { red[wave] = s1; red[4 + wave] = s2; }
  __syncthreads();
  s1 = red[0] + red[1] + red[2] + red[3];
  s2 = red[4] + red[5] + red[6] + red[7];
  float mean = s1 / N;
  float var = s2 / N - mean * mean;
  float rstd = rsqrtf(fmaxf(var, 0.f) + 1e-5f);
  for (int c = tid; c < N; c += 256) {
    float val = (bf2f(ip[c]) - mean) * rstd * gld(g, c, f) + gld(b, c, f);
    if (isfinal && f) ((float*)out)[row * N + c] = val;
    else              ((u16*)out)[row * N + c] = f2bf(val);
  }
}

// ------------------------------------------------------------- wbar ---------
__global__ __launch_bounds__(256) void wbar_k(const void* __restrict__ Wconv,
                                              float* __restrict__ wbar,
                                              const int* __restrict__ dtf)
{
  const int f = dtf[0];
  int g = blockIdx.x;
  int lane = threadIdx.x & 63, wave = threadIdx.x >> 6;
  long base = (long)g * 49152;
  for (int l = wave * 16; l < wave * 16 + 16; ++l) {
    float s = 0.f;
    for (int c = lane; c < 768; c += 64) s += gld(Wconv, base + (long)l * 768 + c, f);
#pragma unroll
    for (int o = 32; o; o >>= 1) s += __shfl_xor(s, o, 64);
    if (lane == 0) wbar[g * 64 + l] = s * (1.f / 768.f);
  }
}

// ------------------------------------------------------------- stats --------
__global__ __launch_bounds__(256) void stats_k(
    const u16* __restrict__ midbf, const float* __restrict__ Mmat, const float* __restrict__ wbar,
    u16* __restrict__ midi, float* __restrict__ pim)
{
  int g = blockIdx.x;
  int row0 = blockIdx.y * 64;
  int tid = threadIdx.x, lane = tid & 63, wave = tid >> 6;
  __shared__ __attribute__((aligned(16))) float Ms[64 * 68];
  __shared__ __attribute__((aligned(16))) float mrow[4][64];
  __shared__ float wb[64];
  {
    int l1 = tid >> 2, c0 = (tid & 3) * 16;
    const float* src = Mmat + (long)g * 4096 + l1 * 64 + c0;
    float* dst = &Ms[l1 * 68 + c0];
#pragma unroll
    for (int e = 0; e < 16; e += 4) *(f32x4*)(dst + e) = *(const f32x4*)(src + e);
  }
  if (tid < 64) wb[tid] = wbar[g * 64 + tid];
  __syncthreads();
  for (int t = 0; t < 16; ++t) {
    int r = row0 + wave * 16 + t;            // flat (b*257+j) row
    bool valid = r < 1028;
    float m = valid ? bf2f(midbf[(long)r * 6656 + g * 64 + lane]) : 0.f;
    mrow[wave][lane] = m;
    __syncthreads();
    float rowdot = 0.f;
    const f32x4* Mr = (const f32x4*)&Ms[lane * 68];
    const f32x4* xr = (const f32x4*)&mrow[wave][0];
#pragma unroll
    for (int c = 0; c < 16; ++c) {
      f32x4 a = Mr[c], x = xr[c];
      rowdot = fmaf(a.x, x.x, rowdot); rowdot = fmaf(a.y, x.y, rowdot);
      rowdot = fmaf(a.z, x.z, rowdot); rowdot = fmaf(a.w, x.w, rowdot);
    }
    float mup = m * wb[lane];
    float q2p = m * rowdot;
#pragma unroll
    for (int o = 32; o; o >>= 1) { mup += __shfl_xor(mup, o, 64); q2p += __shfl_xor(q2p, o, 64); }
    float var = q2p - mup * mup;
    float inv = rsqrtf(fmaxf(var, 0.f) + 1e-5f);
    if (valid) {
      int bb = r / 257, j = r - bb * 257;
      long base = ((long)bb * 104 + g) * 257 + j;
      midi[base * 64 + lane] = f2bf(inv * m);
      if (lane == 0) pim[base] = inv * mup;
    }
    __syncthreads();
  }
}

// ------------------------------------------------------------- softmax ------
__global__ __launch_bounds__(256) void softmax_k(
    const float* __restrict__ simf, const float* __restrict__ pim,
    u16* __restrict__ Abf, u16* __restrict__ A2bf, float* __restrict__ s_sh)
{
  int bh = blockIdx.x;
  int b = bh / 6, h = bh - b * 6;
  int tid = threadIdx.x, lane = tid & 63, wave = tid >> 6;
  int i = blockIdx.y * 4 + wave;
  int g = i % 104, rq = i / 104;
  const float* sp_ = simf + ((long)bh * 416 + i) * 257;
  float s[5];
#pragma unroll
  for (int jc = 0; jc < 5; ++jc) {
    int j = jc * 64 + lane;
    s[jc] = (j < 257) ? sp_[j] : -1e30f;
  }
  float mx = -1e30f;
#pragma unroll
  for (int jc = 0; jc < 5; ++jc) mx = fmaxf(mx, s[jc]);
#pragma unroll
  for (int o = 32; o; o >>= 1) mx = fmaxf(mx, __shfl_xor(mx, o, 64));
  float p[5], sum = 0.f, sp = 0.f;
  long pimb = ((long)b * 104 + g) * 257;
#pragma unroll
  for (int jc = 0; jc < 5; ++jc) {
    int j = jc * 64 + lane;
    float pv = 0.f;
    if (j < 257) { pv = __expf(s[jc] - mx); sp = fmaf(pv, pim[pimb + j], sp); }
    p[jc] = pv; sum += pv;
  }
#pragma unroll
  for (int o = 32; o; o >>= 1) { sum += __shfl_xor(sum, o, 64); sp += __shfl_xor(sp, o, 64); }
  float rs = 1.f / sum;
  long arow  = ((long)bh * 416 + i) * 264;
  long a2row = (((long)b * 104 + g) * 24 + h * 4 + rq) * 264;
#pragma unroll
  for (int jc = 0; jc < 5; ++jc) {
    int j = jc * 64 + lane;
    if (j < 257) { u16 pb = f2bf(p[jc] * rs); Abf[arow + j] = pb; A2bf[a2row + j] = pb; }
    else if (j < 264) { Abf[arow + j] = 0; A2bf[a2row + j] = 0; }
  }
  if (lane == 0) s_sh[(long)bh * 416 + i] = sp * rs;
}

// ------------------------------------------------------------- combine ------
__global__ __launch_bounds__(256) void combine_k(
    const u16* __restrict__ O, const float* __restrict__ s_sh, const float* __restrict__ c_buf,
    const void* __restrict__ gv2, const void* __restrict__ bv2,
    u16* __restrict__ opbf, const int* __restrict__ dtf)
{
  const int f = dtf[0];
  int bi = blockIdx.x;
  int b = bi / 416, i = bi - b * 416;
  int g = i % 104, rq = i / 104;
  int tid = threadIdx.x;
  long obase = ((long)b * 104 + g) * 24 * 768;
#pragma unroll
  for (int it = 0; it < 3; ++it) {
    int d = tid + it * 256;
    int h = d >> 7, dh = d & 127;
    float o = bf2f(O[obase + (long)(h * 4 + rq) * 768 + d]);
    float ssh = s_sh[((long)b * 6 + h) * 416 + i];
    float val = gld(gv2, d, f) * (o - ssh) + gld(bv2, d, f)
              + c_buf[(((long)b * 6 + h) * 416 + i) * 128 + dh];
    opbf[((long)b * 416 + i) * 768 + d] = f2bf(val);
  }
}

// ---------------------------------------------------------------- host ------
static void launch_gemm(const void* A, const void* B, float* Cf, u16* Cb, int obf,
                        int M, int N, int K, int lda, int ldb, int ldc,
                        long sAo, long sAi, int adiv, long sBo, long sBi, int bdiv,
                        long sC, int zoff, int Z, int btrans, float alpha,
                        const int* dtf, int aSel, int bSel, hipStream_t st)
{
  dim3 grid((M + 63) / 64, (N + 63) / 64, Z);
  gemm_bf16<<<grid, dim3(256), 0, st>>>(A, B, Cf, Cb, obf, M, N, K, lda, ldb, ldc,
                                        sAo, sAi, adiv, sBo, sBi, bdiv,
                                        sC, zoff, btrans, alpha, dtf, aSel, bSel);
}

extern "C" void kernel_launch(void* const* d_in, const int* in_sizes, int n_in,
                              void* d_out, int out_size, void* d_ws, size_t ws_size,
                              hipStream_t stream)
{
  (void)in_sizes; (void)n_in;
  const void* x   = d_in[0];
  const void* ctx = d_in[1];
  const void* Wq  = d_in[2];
  const void* gq  = d_in[3];
  const void* bq  = d_in[4];
  const void* Wk  = d_in[5];
  const void* gk  = d_in[6];
  const void* bk  = d_in[7];
  const void* Wv  = d_in[8];
  const void* gv1 = d_in[9];
  const void* bv1 = d_in[10];
  const void* Wcv = d_in[11];
  const void* gv2 = d_in[12];
  const void* bv2 = d_in[13];
  const void* Wo  = d_in[14];
  const void* go  = d_in[15];
  const void* bo  = d_in[16];

  // -------- workspace layout --------
  const size_t SZ_FLAG = 256;
  const size_t SZ_QBF  = 2555904;    // 1664x768 bf16 (reused as final-GEMM scratch)
  const size_t SZ_KBF  = 1579008;    // 1028x768 bf16
  const size_t SZ_MID  = 13684736;   // WqT/WkT (pre-mid) -> midbf -> simf -> c_buf+Tb16/WoT
  const size_t SZ_MM   = 1703936;    // Mmat; later (+WB+MIDI+PIM): Obf 15.34MB
  const size_t SZ_WB   = 26624;
  const size_t SZ_MIDI = 13684736;
  const size_t SZ_PIM  = 427648;
  const size_t SZ_ABF  = 5271552;    // xb -> WvT (spans ABF+A2) -> Abf -> opbf
  const size_t SZ_A2   = 5271552;
  const size_t SZ_SSH  = 39936;
  const size_t SZ_CB   = 1579008;    // ctx bf16 copy (NEW, persistent)
  const size_t REQUIRED = SZ_FLAG + SZ_QBF + SZ_KBF + SZ_MID + SZ_MM + SZ_WB +
                          SZ_MIDI + SZ_PIM + SZ_ABF + SZ_A2 + SZ_SSH + SZ_CB;  // 45,824,896

  if (ws_size < REQUIRED) {  // diagnostic: report ws_size in MB via output
    fill_k<<<(out_size + 255) / 256, 256, 0, stream>>>((u16*)d_out, (float)(ws_size >> 20), out_size);
    return;
  }

  char* p = (char*)d_ws;
  int*   dtf   = (int*)  p;                 p += SZ_FLAG;
  u16*   qbf   = (u16*)  p;                 p += SZ_QBF;
  u16*   kbf   = (u16*)  p;                 p += SZ_KBF;
  char*  midrg = p;                         p += SZ_MID;
  char*  mmrg  = p;                         p += SZ_MM;
  float* wbar  = (float*)p;                 p += SZ_WB;
  u16*   midi  = (u16*)  p;                 p += SZ_MIDI;
  float* pim   = (float*)p;                 p += SZ_PIM;
  char*  abfrg = p;                         p += SZ_ABF;
  u16*   A2bf  = (u16*)  p;                 p += SZ_A2;
  float* s_sh  = (float*)p;                 p += SZ_SSH;
  u16*   cb    = (u16*)  p;                 p += SZ_CB;

  u16*   WqT   = (u16*)midrg;               // live: trans .. q GEMM (1.18MB)
  u16*   WkT   = (u16*)midrg;               // live: trans .. k GEMM
  u16*   midbf = (u16*)midrg;               // live: mid GEMM .. stats_k
  float* simf  = (float*)midrg;             // live: sim GEMM .. softmax (10.27MB)
  float* c_buf = (float*)midrg;             // live: c GEMM .. combine (5.11MB)
  u16*   Tb16  = (u16*)(midrg + 5111808);   // live: T GEMM .. O GEMM (1.28MB)
  u16*   WoT   = (u16*)(midrg + 5111808);   // live: trans (post-O) .. final GEMM (1.18MB)
  float* Mmat  = (float*)mmrg;              // live: gram .. stats_k
  u16*   Obf   = (u16*)mmrg;                // live: O GEMM .. combine (15.34MB over MM..PIM)
  u16*   xb    = (u16*)abfrg;               // live: conv .. q GEMM (2.56MB)
  u16*   WvT   = (u16*)abfrg;               // live: trans .. mid GEMM (10.22MB over ABF+A2)
  u16*   Abf   = (u16*)abfrg;               // live: softmax .. c GEMM
  u16*   opbf  = (u16*)abfrg;               // live: combine .. final GEMM

  probe_k<<<1, 256, 0, stream>>>((const u32*)x, dtf);

  // ---- prep: bf16 copies / transposes ----
  convb_k<<<(1277952 / 8 + 255) / 256, 256, 0, stream>>>(x, xb, 1277952, dtf);
  convb_k<<<(789504 / 8 + 255) / 256, 256, 0, stream>>>(ctx, cb, 789504, dtf);
  transb_k<<<dim3(24, 24), 256, 0, stream>>>(Wq, WqT, 768, 768, dtf);

  // q = LN(x @ Wq) : btrans, pure bf16
  launch_gemm(xb, WqT, nullptr, qbf, 1, 1664, 768, 768, 768, 768, 768,
              0, 0, 1, 0, 0, 1, 0, 0, 1, 1, 1.f, dtf, 0, 0, stream);
  ln_rows<<<1664, 256, 0, stream>>>(qbf, gq, bq, qbf, 768, dtf, 0);

  transb_k<<<dim3(24, 24), 256, 0, stream>>>(Wk, WkT, 768, 768, dtf);
  // k = LN(ctx @ Wk)
  launch_gemm(cb, WkT, nullptr, kbf, 1, 1028, 768, 768, 768, 768, 768,
              0, 0, 1, 0, 0, 1, 0, 0, 1, 1, 1.f, dtf, 0, 0, stream);
  ln_rows<<<1028, 256, 0, stream>>>(kbf, gk, bk, kbf, 768, dtf, 0);

  transb_k<<<dim3(208, 24), 256, 0, stream>>>(Wv, WvT, 768, 6656, dtf);
  // mid = LN(ctx @ Wv)
  launch_gemm(cb, WvT, nullptr, midbf, 1, 1028, 6656, 768, 768, 768, 6656,
              0, 0, 1, 0, 0, 1, 0, 0, 1, 1, 1.f, dtf, 0, 0, stream);
  ln_rows<<<1028, 256, 0, stream>>>(midbf, gv1, bv1, midbf, 6656, dtf, 0);

  // Gram: M[g] = Wconv[g] @ Wconv[g]^T / 768   (z=104, flag loads)
  launch_gemm(Wcv, Wcv, Mmat, nullptr, 0, 64, 64, 768, 768, 768, 64,
              49152, 0, 1, 49152, 0, 1, 4096, 0, 104, 1, 1.f / 768.f, dtf, 1, 1, stream);
  wbar_k<<<104, 256, 0, stream>>>(Wcv, wbar, dtf);
  stats_k<<<dim3(104, 17), 256, 0, stream>>>(midbf, Mmat, wbar, midi, pim);

  // sim = scale^2 * q @ k^T   (z = b*6+h, btrans, fp32 out)
  launch_gemm(qbf, kbf, simf, nullptr, 0, 416, 257, 128, 768, 768, 257,
              319488, 128, 6, 197376, 128, 6, 106912, 0, 24, 1,
              0.08838834764831845f, dtf, 0, 0, stream);
  softmax_k<<<dim3(24, 104), 256, 0, stream>>>(simf, pim, Abf, A2bf, s_sh);

  // c = A @ ctx_head   (z = b*6+h; B = cb bf16)
  launch_gemm(Abf, cb, c_buf, nullptr, 0, 416, 128, 257, 264, 768, 128,
              109824, 0, 1, 197376, 128, 6, 53248, 0, 24, 0, 1.f, dtf, 0, 0, stream);
  // T = A2 @ midi      (z = b*104+g)
  launch_gemm(A2bf, midi, nullptr, Tb16, 1, 24, 64, 257, 264, 64, 64,
              6336, 0, 1, 16448, 0, 1, 1536, 0, 416, 0, 1.f, dtf, 0, 0, stream);
  // O = T @ Wconv[g]   (z = b*104+g, flag B loads)
  launch_gemm(Tb16, Wcv, nullptr, Obf, 1, 24, 768, 64, 64, 768, 768,
              1536, 0, 1, 0, 49152, 104, 18432, 0, 416, 0, 1.f, dtf, 0, 1, stream);

  transb_k<<<dim3(24, 24), 256, 0, stream>>>(Wo, WoT, 768, 768, dtf);  // Tb16 dead after O
  combine_k<<<1664, 256, 0, stream>>>(Obf, s_sh, c_buf, gv2, bv2, opbf, dtf);
  // out = LN(out_pre @ Wo): GEMM -> qbf scratch, LN -> d_out (flag dtype)
  launch_gemm(opbf, WoT, nullptr, qbf, 1, 1664, 768, 768, 768, 768, 768,
              0, 0, 1, 0, 0, 1, 0, 0, 1, 1, 1.f, dtf, 0, 0, stream);
  ln_rows<<<1664, 256, 0, stream>>>(qbf, go, bo, d_out, 768, dtf, 1);
}

// Round 8
// 425.683 us; speedup vs baseline: 2.0698x; 1.1156x over previous
//
#include <hip/hip_runtime.h>

// SubjBasisGenerator fused pipeline. B=4 NQ=416 NC=257 D=768 H=6 DH=128 G=104 R=4 LORA=64
// R8: wbar_k parallelized (was 60us at 104 blocks / 2% HBM -> one wave per row,
// 1664 blocks); ln_rows vectorized 8-wide (scalar bf16 loads were ~2.4 TB/s).
//
// Algebra: the grouped-conv+LN v-path decomposes exactly (no (B,G,NC,768) tensor):
//   sum_j A_j v_j = gv2*( (sum_j A_j inv_j mid_j)@Wconv[g] - sum_j A_j inv_j mu_j )
//                   + bv2 + (A @ ctx)

typedef unsigned short u16;
typedef unsigned int   u32;
typedef __attribute__((ext_vector_type(4))) float f32x4;
typedef __attribute__((ext_vector_type(4))) u32   u32x4;
typedef __attribute__((ext_vector_type(8))) short bf16x8;

__device__ __forceinline__ float bf2f(u16 v) { return __uint_as_float(((u32)v) << 16); }
__device__ __forceinline__ u16 f2bf(float f) {
  u32 u = __float_as_uint(f);
  u32 r = u + 0x7fffu + ((u >> 16) & 1u);  // RNE
  return (u16)(r >> 16);
}
__device__ __forceinline__ float gld(const void* p, long idx, int f32) {
  return f32 ? ((const float*)p)[idx] : bf2f(((const u16*)p)[idx]);
}

// ------------------------------------------------------------ dtype probe ---
__global__ __launch_bounds__(256) void probe_k(const u32* __restrict__ xw, int* __restrict__ flag) {
  int tid = threadIdx.x, c = 0;
  for (int i = tid; i < 4096; i += 256) {
    u16 lo = (u16)(xw[i] & 0xffffu);
    float a = fabsf(bf2f(lo));
    if (lo == 0 || (a >= 1e-3f && a <= 32.f)) ++c;
  }
#pragma unroll
  for (int o = 32; o; o >>= 1) c += __shfl_xor(c, o, 64);
  __shared__ int r[4];
  if ((tid & 63) == 0) r[tid >> 6] = c;
  __syncthreads();
  if (tid == 0) flag[0] = (r[0] + r[1] + r[2] + r[3] >= 2048) ? 0 : 1;  // 1 = fp32
}

// ------------------------------------------------------------ diag fill -----
__global__ __launch_bounds__(256) void fill_k(u16* p, float v, int n) {
  int i = blockIdx.x * 256 + threadIdx.x;
  if (i < n) p[i] = f2bf(v);
}

// ------------------------------------------------------- ext -> bf16 copy ---
__global__ __launch_bounds__(256) void convb_k(const void* __restrict__ in, u16* __restrict__ out,
                                               int n, const int* __restrict__ dtf) {
  const int f = dtf[0];
  int i = (blockIdx.x * 256 + threadIdx.x) * 8;
  if (i + 8 <= n) {
    if (f) {
      const float* ip = (const float*)in + i;
      f32x4 a = *(const f32x4*)ip, b = *(const f32x4*)(ip + 4);
      u32x4 q = { (u32)f2bf(a.x) | ((u32)f2bf(a.y) << 16),
                  (u32)f2bf(a.z) | ((u32)f2bf(a.w) << 16),
                  (u32)f2bf(b.x) | ((u32)f2bf(b.y) << 16),
                  (u32)f2bf(b.z) | ((u32)f2bf(b.w) << 16) };
      *(u32x4*)(out + i) = q;
    } else {
      *(u32x4*)(out + i) = *(const u32x4*)((const u16*)in + i);
    }
  } else {
    for (; i < n; ++i) out[i] = f2bf(gld(in, i, f));
  }
}

// ------------------------------------- ext [K,N] -> bf16 [N,K] transpose ----
__global__ __launch_bounds__(256) void transb_k(const void* __restrict__ in, u16* __restrict__ out,
                                                int K, int N, const int* __restrict__ dtf) {
  const int f = dtf[0];
  __shared__ float s[32][33];
  int n0 = blockIdx.x * 32, k0 = blockIdx.y * 32;
  int tx = threadIdx.x & 31, ty = threadIdx.x >> 5;  // 32 x 8
#pragma unroll
  for (int i = 0; i < 32; i += 8) {
    int k = k0 + ty + i, n = n0 + tx;
    float v = 0.f;
    if (k < K && n < N) v = gld(in, (long)k * N + n, f);
    s[ty + i][tx] = v;
  }
  __syncthreads();
#pragma unroll
  for (int i = 0; i < 32; i += 8) {
    int n = n0 + ty + i, k = k0 + tx;
    if (n < N && k < K) out[(long)n * K + k] = f2bf(s[tx][ty + i]);
  }
}

// ---------------------------------------------------------------- GEMM ------
// C = alpha*(A@B) (or A@B^T if btrans). aSel/bSel=1: operand follows dtype flag;
// 0: always-bf16 internal. Batch: zg = blockIdx.z + zoff;
//   aoff=(zg/adiv)*sAo+(zg%adiv)*sAi; boff=(zg/bdiv)*sBo+(zg%bdiv)*sBi;
//   C += blockIdx.z * sC. N-bounds guarded. 64x64 tile, BK=32, 4 waves,
// 2x2 mfma_f32_16x16x32_bf16 per wave.
#define LDS_S 40

__global__ __launch_bounds__(256) void gemm_bf16(
    const void* __restrict__ A, const void* __restrict__ B,
    float* __restrict__ Cf, u16* __restrict__ Cb, int obf,
    int M, int N, int K, int lda, int ldb, int ldc,
    long sAo, long sAi, int adiv, long sBo, long sBi, int bdiv,
    long sC, int zoff, int btrans, float alpha,
    const int* __restrict__ dtf, int aSel, int bSel)
{
  const int f = dtf[0];
  const int af32 = aSel & f, bf32 = bSel & f;
  const int zl = blockIdx.z, zg = zl + zoff;
  const long aoff = (long)(zg / adiv) * sAo + (long)(zg % adiv) * sAi;
  const long boff = (long)(zg / bdiv) * sBo + (long)(zg % bdiv) * sBi;
  const u16*   A16 = (const u16*)A + aoff;
  const float* A32 = (const float*)A + aoff;
  const u16*   B16 = (const u16*)B + boff;
  const float* B32 = (const float*)B + boff;

  __shared__ __attribute__((aligned(16))) u16 As[64 * LDS_S];
  __shared__ __attribute__((aligned(16))) u16 Bs[64 * LDS_S];

  const int tid = threadIdx.x;
  const int lane = tid & 63, wave = tid >> 6;
  const int m0 = blockIdx.x * 64, n0 = blockIdx.y * 64;
  const int wm = (wave >> 1) * 32, wn = (wave & 1) * 32;
  const int fm = lane & 15, fq = lane >> 4;

  const int ar = tid >> 2, ak = (tid & 3) * 8;   // A staging: row, k-offset
  const int bk = tid >> 3, bn = (tid & 7) * 8;   // B staging (non-trans path)

  f32x4 acc[2][2];
  const f32x4 zero4 = {0.f, 0.f, 0.f, 0.f};
#pragma unroll
  for (int a_ = 0; a_ < 2; ++a_)
#pragma unroll
    for (int b_ = 0; b_ < 2; ++b_) acc[a_][b_] = zero4;

  for (int k0 = 0; k0 < K; k0 += 32) {
    // ---- stage A tile (64 x 32) ----
    {
      int gm = m0 + ar, gk = k0 + ak;
      long idx = (long)gm * lda + gk;
      if (gm < M && gk + 8 <= K) {
        if (af32) {
          f32x4 u = *(const f32x4*)(A32 + idx), v = *(const f32x4*)(A32 + idx + 4);
          u32x4 q = { (u32)f2bf(u.x) | ((u32)f2bf(u.y) << 16),
                      (u32)f2bf(u.z) | ((u32)f2bf(u.w) << 16),
                      (u32)f2bf(v.x) | ((u32)f2bf(v.y) << 16),
                      (u32)f2bf(v.z) | ((u32)f2bf(v.w) << 16) };
          *(u32x4*)&As[ar * LDS_S + ak] = q;
        } else {
          *(u32x4*)&As[ar * LDS_S + ak] = *(const u32x4*)(A16 + idx);
        }
      } else {
#pragma unroll
        for (int e = 0; e < 8; ++e) {
          u16 v = 0;
          if (gm < M && gk + e < K) v = f2bf(gld(A, aoff + idx + e, af32));
          As[ar * LDS_S + ak + e] = v;
        }
      }
    }
    // ---- stage B tile as Bs[n][k] (64 x 32) ----
    if (btrans) {
      int gn = n0 + ar, gk = k0 + ak;
      long idx = (long)gn * ldb + gk;
      if (gn < N && gk + 8 <= K) {
        if (bf32) {
          f32x4 u = *(const f32x4*)(B32 + idx), v = *(const f32x4*)(B32 + idx + 4);
          u32x4 q = { (u32)f2bf(u.x) | ((u32)f2bf(u.y) << 16),
                      (u32)f2bf(u.z) | ((u32)f2bf(u.w) << 16),
                      (u32)f2bf(v.x) | ((u32)f2bf(v.y) << 16),
                      (u32)f2bf(v.z) | ((u32)f2bf(v.w) << 16) };
          *(u32x4*)&Bs[ar * LDS_S + ak] = q;
        } else {
          *(u32x4*)&Bs[ar * LDS_S + ak] = *(const u32x4*)(B16 + idx);
        }
      } else {
#pragma unroll
        for (int e = 0; e < 8; ++e) {
          u16 v = 0;
          if (gn < N && gk + e < K) v = f2bf(gld(B, boff + idx + e, bf32));
          Bs[ar * LDS_S + ak + e] = v;
        }
      }
    } else {
      int gk = k0 + bk;
      long idx = (long)gk * ldb + n0 + bn;
      u16 tmp[8];
      if (gk < K) {
        if (bf32) {
          f32x4 u = *(const f32x4*)(B32 + idx), v = *(const f32x4*)(B32 + idx + 4);
          tmp[0] = f2bf(u.x); tmp[1] = f2bf(u.y); tmp[2] = f2bf(u.z); tmp[3] = f2bf(u.w);
          tmp[4] = f2bf(v.x); tmp[5] = f2bf(v.y); tmp[6] = f2bf(v.z); tmp[7] = f2bf(v.w);
        } else {
          u32x4 v = *(const u32x4*)(B16 + idx);
          tmp[0] = (u16)(v.x & 0xffff); tmp[1] = (u16)(v.x >> 16);
          tmp[2] = (u16)(v.y & 0xffff); tmp[3] = (u16)(v.y >> 16);
          tmp[4] = (u16)(v.z & 0xffff); tmp[5] = (u16)(v.z >> 16);
          tmp[6] = (u16)(v.w & 0xffff); tmp[7] = (u16)(v.w >> 16);
        }
      } else {
#pragma unroll
        for (int e = 0; e < 8; ++e) tmp[e] = 0;
      }
      int rot = tid & 7;  // spread LDS bank writes
#pragma unroll
      for (int e = 0; e < 8; ++e) {
        int ee = (e + rot) & 7;
        Bs[(bn + ee) * LDS_S + bk] = tmp[ee];
      }
    }
    __syncthreads();
    {
      bf16x8 fa[2], fb[2];
      fa[0] = *(const bf16x8*)&As[(wm +      fm) * LDS_S + fq * 8];
      fa[1] = *(const bf16x8*)&As[(wm + 16 + fm) * LDS_S + fq * 8];
      fb[0] = *(const bf16x8*)&Bs[(wn +      fm) * LDS_S + fq * 8];
      fb[1] = *(const bf16x8*)&Bs[(wn + 16 + fm) * LDS_S + fq * 8];
#pragma unroll
      for (int mt = 0; mt < 2; ++mt)
#pragma unroll
        for (int nt = 0; nt < 2; ++nt)
          acc[mt][nt] = __builtin_amdgcn_mfma_f32_16x16x32_bf16(fa[mt], fb[nt], acc[mt][nt], 0, 0, 0);
    }
    __syncthreads();
  }
  // epilogue: C/D layout col=lane&15, row=(lane>>4)*4+reg (m89-verified)
#pragma unroll
  for (int mt = 0; mt < 2; ++mt)
#pragma unroll
    for (int nt = 0; nt < 2; ++nt)
#pragma unroll
      for (int rr = 0; rr < 4; ++rr) {
        int gm = m0 + wm + mt * 16 + fq * 4 + rr;
        int gn = n0 + wn + nt * 16 + fm;
        if (gm < M && gn < N) {
          float v = alpha * acc[mt][nt][rr];
          if (obf) Cb[(long)zl * sC + (long)gm * ldc + gn] = f2bf(v);
          else     Cf[(long)zl * sC + (long)gm * ldc + gn] = v;
        }
      }
}

// ------------------------------------------------------------- row LN -------
// 8-wide vectorized. N must be a multiple of 8 (768 / 6656 are).
__global__ __launch_bounds__(256) void ln_rows(
    const u16* __restrict__ in, const void* __restrict__ g, const void* __restrict__ b,
    void* __restrict__ out, int N, const int* __restrict__ dtf, int isfinal)
{
  const int f = dtf[0];
  long row = blockIdx.x;
  const u16* ip = in + row * N;
  int tid = threadIdx.x, lane = tid & 63, wave = tid >> 6;
  const int nv = N >> 3;
  float s1 = 0.f, s2 = 0.f;
  for (int c8 = tid; c8 < nv; c8 += 256) {
    u32x4 v = *(const u32x4*)(ip + c8 * 8);
    float e0 = bf2f((u16)(v.x & 0xffff)), e1 = bf2f((u16)(v.x >> 16));
    float e2 = bf2f((u16)(v.y & 0xffff)), e3 = bf2f((u16)(v.y >> 16));
    float e4 = bf2f((u16)(v.z & 0xffff)), e5 = bf2f((u16)(v.z >> 16));
    float e6 = bf2f((u16)(v.w & 0xffff)), e7 = bf2f((u16)(v.w >> 16));
    s1 += ((e0 + e1) + (e2 + e3)) + ((e4 + e5) + (e6 + e7));
    s2 += ((e0*e0 + e1*e1) + (e2*e2 + e3*e3)) + ((e4*e4 + e5*e5) + (e6*e6 + e7*e7));
  }
#pragma unroll
  for (int o = 32; o; o >>= 1) { s1 += __shfl_xor(s1, o, 64); s2 += __shfl_xor(s2, o, 64); }
  __shared__ float red[8];
  if (lane == 0) { red[wave] = s1; red[4 + wave] = s2; }
  __syncthreads();
  s1 = red[0] + red[1] + red[2] + red[3];
  s2 = red[4] + red[5] + red[6] + red[7];
  float mean = s1 / N;
  float var = s2 / N - mean * mean;
  float rstd = rsqrtf(fmaxf(var, 0.f) + 1e-5f);
  for (int c8 = tid; c8 < nv; c8 += 256) {
    int c = c8 * 8;
    u32x4 v = *(const u32x4*)(ip + c);
    float e[8];
    e[0] = bf2f((u16)(v.x & 0xffff)); e[1] = bf2f((u16)(v.x >> 16));
    e[2] = bf2f((u16)(v.y & 0xffff)); e[3] = bf2f((u16)(v.y >> 16));
    e[4] = bf2f((u16)(v.z & 0xffff)); e[5] = bf2f((u16)(v.z >> 16));
    e[6] = bf2f((u16)(v.w & 0xffff)); e[7] = bf2f((u16)(v.w >> 16));
    float gg[8], bb[8];
    if (f) {
      const float* gp = (const float*)g + c; const float* bp = (const float*)b + c;
      f32x4 g0 = *(const f32x4*)gp, g1 = *(const f32x4*)(gp + 4);
      f32x4 b0 = *(const f32x4*)bp, b1 = *(const f32x4*)(bp + 4);
      gg[0]=g0.x; gg[1]=g0.y; gg[2]=g0.z; gg[3]=g0.w; gg[4]=g1.x; gg[5]=g1.y; gg[6]=g1.z; gg[7]=g1.w;
      bb[0]=b0.x; bb[1]=b0.y; bb[2]=b0.z; bb[3]=b0.w; bb[4]=b1.x; bb[5]=b1.y; bb[6]=b1.z; bb[7]=b1.w;
    } else {
      u32x4 gv = *(const u32x4*)((const u16*)g + c);
      u32x4 bv = *(const u32x4*)((const u16*)b + c);
      gg[0]=bf2f((u16)(gv.x&0xffff)); gg[1]=bf2f((u16)(gv.x>>16));
      gg[2]=bf2f((u16)(gv.y&0xffff)); gg[3]=bf2f((u16)(gv.y>>16));
      gg[4]=bf2f((u16)(gv.z&0xffff)); gg[5]=bf2f((u16)(gv.z>>16));
      gg[6]=bf2f((u16)(gv.w&0xffff)); gg[7]=bf2f((u16)(gv.w>>16));
      bb[0]=bf2f((u16)(bv.x&0xffff)); bb[1]=bf2f((u16)(bv.x>>16));
      bb[2]=bf2f((u16)(bv.y&0xffff)); bb[3]=bf2f((u16)(bv.y>>16));
      bb[4]=bf2f((u16)(bv.z&0xffff)); bb[5]=bf2f((u16)(bv.z>>16));
      bb[6]=bf2f((u16)(bv.w&0xffff)); bb[7]=bf2f((u16)(bv.w>>16));
    }
    float o_[8];
#pragma unroll
    for (int e2i = 0; e2i < 8; ++e2i) o_[e2i] = (e[e2i] - mean) * rstd * gg[e2i] + bb[e2i];
    if (isfinal && f) {
      float* op = (float*)out + row * N + c;
      f32x4 o0 = {o_[0], o_[1], o_[2], o_[3]}, o1 = {o_[4], o_[5], o_[6], o_[7]};
      *(f32x4*)op = o0; *(f32x4*)(op + 4) = o1;
    } else {
      u32x4 q = { (u32)f2bf(o_[0]) | ((u32)f2bf(o_[1]) << 16),
                  (u32)f2bf(o_[2]) | ((u32)f2bf(o_[3]) << 16),
                  (u32)f2bf(o_[4]) | ((u32)f2bf(o_[5]) << 16),
                  (u32)f2bf(o_[6]) | ((u32)f2bf(o_[7]) << 16) };
      *(u32x4*)((u16*)out + row * N + c) = q;
    }
  }
}

// ------------------------------------------------------------- wbar ---------
// R8: one wave per (g,l) row. grid 1664 x 4 waves = 6656 rows.
__global__ __launch_bounds__(256) void wbar_k(const void* __restrict__ Wconv,
                                              float* __restrict__ wbar,
                                              const int* __restrict__ dtf)
{
  const int f = dtf[0];
  int r = blockIdx.x * 4 + (threadIdx.x >> 6);   // row 0..6655 = g*64+l
  int lane = threadIdx.x & 63;
  long base = (long)r * 768;
  float s = 0.f;
  for (int c = lane; c < 768; c += 64) s += gld(Wconv, base + c, f);
#pragma unroll
  for (int o = 32; o; o >>= 1) s += __shfl_xor(s, o, 64);
  if (lane == 0) wbar[r] = s * (1.f / 768.f);
}

// ------------------------------------------------------------- stats --------
__global__ __launch_bounds__(256) void stats_k(
    const u16* __restrict__ midbf, const float* __restrict__ Mmat, const float* __restrict__ wbar,
    u16* __restrict__ midi, float* __restrict__ pim)
{
  int g = blockIdx.x;
  int row0 = blockIdx.y * 64;
  int tid = threadIdx.x, lane = tid & 63, wave = tid >> 6;
  __shared__ __attribute__((aligned(16))) float Ms[64 * 68];
  __shared__ __attribute__((aligned(16))) float mrow[4][64];
  __shared__ float wb[64];
  {
    int l1 = tid >> 2, c0 = (tid & 3) * 16;
    const float* src = Mmat + (long)g * 4096 + l1 * 64 + c0;
    float* dst = &Ms[l1 * 68 + c0];
#pragma unroll
    for (int e = 0; e < 16; e += 4) *(f32x4*)(dst + e) = *(const f32x4*)(src + e);
  }
  if (tid < 64) wb[tid] = wbar[g * 64 + tid];
  __syncthreads();
  for (int t = 0; t < 16; ++t) {
    int r = row0 + wave * 16 + t;            // flat (b*257+j) row
    bool valid = r < 1028;
    float m = valid ? bf2f(midbf[(long)r * 6656 + g * 64 + lane]) : 0.f;
    mrow[wave][lane] = m;
    __syncthreads();
    float rowdot = 0.f;
    const f32x4* Mr = (const f32x4*)&Ms[lane * 68];
    const f32x4* xr = (const f32x4*)&mrow[wave][0];
#pragma unroll
    for (int c = 0; c < 16; ++c) {
      f32x4 a = Mr[c], x = xr[c];
      rowdot = fmaf(a.x, x.x, rowdot); rowdot = fmaf(a.y, x.y, rowdot);
      rowdot = fmaf(a.z, x.z, rowdot); rowdot = fmaf(a.w, x.w, rowdot);
    }
    float mup = m * wb[lane];
    float q2p = m * rowdot;
#pragma unroll
    for (int o = 32; o; o >>= 1) { mup += __shfl_xor(mup, o, 64); q2p += __shfl_xor(q2p, o, 64); }
    float var = q2p - mup * mup;
    float inv = rsqrtf(fmaxf(var, 0.f) + 1e-5f);
    if (valid) {
      int bb = r / 257, j = r - bb * 257;
      long base = ((long)bb * 104 + g) * 257 + j;
      midi[base * 64 + lane] = f2bf(inv * m);
      if (lane == 0) pim[base] = inv * mup;
    }
    __syncthreads();
  }
}

// ------------------------------------------------------------- softmax ------
__global__ __launch_bounds__(256) void softmax_k(
    const float* __restrict__ simf, const float* __restrict__ pim,
    u16* __restrict__ Abf, u16* __restrict__ A2bf, float* __restrict__ s_sh)
{
  int bh = blockIdx.x;
  int b = bh / 6, h = bh - b * 6;
  int tid = threadIdx.x, lane = tid & 63, wave = tid >> 6;
  int i = blockIdx.y * 4 + wave;
  int g = i % 104, rq = i / 104;
  const float* sp_ = simf + ((long)bh * 416 + i) * 257;
  float s[5];
#pragma unroll
  for (int jc = 0; jc < 5; ++jc) {
    int j = jc * 64 + lane;
    s[jc] = (j < 257) ? sp_[j] : -1e30f;
  }
  float mx = -1e30f;
#pragma unroll
  for (int jc = 0; jc < 5; ++jc) mx = fmaxf(mx, s[jc]);
#pragma unroll
  for (int o = 32; o; o >>= 1) mx = fmaxf(mx, __shfl_xor(mx, o, 64));
  float p[5], sum = 0.f, sp = 0.f;
  long pimb = ((long)b * 104 + g) * 257;
#pragma unroll
  for (int jc = 0; jc < 5; ++jc) {
    int j = jc * 64 + lane;
    float pv = 0.f;
    if (j < 257) { pv = __expf(s[jc] - mx); sp = fmaf(pv, pim[pimb + j], sp); }
    p[jc] = pv; sum += pv;
  }
#pragma unroll
  for (int o = 32; o; o >>= 1) { sum += __shfl_xor(sum, o, 64); sp += __shfl_xor(sp, o, 64); }
  float rs = 1.f / sum;
  long arow  = ((long)bh * 416 + i) * 264;
  long a2row = (((long)b * 104 + g) * 24 + h * 4 + rq) * 264;
#pragma unroll
  for (int jc = 0; jc < 5; ++jc) {
    int j = jc * 64 + lane;
    if (j < 257) { u16 pb = f2bf(p[jc] * rs); Abf[arow + j] = pb; A2bf[a2row + j] = pb; }
    else if (j < 264) { Abf[arow + j] = 0; A2bf[a2row + j] = 0; }
  }
  if (lane == 0) s_sh[(long)bh * 416 + i] = sp * rs;
}

// ------------------------------------------------------------- combine ------
__global__ __launch_bounds__(256) void combine_k(
    const u16* __restrict__ O, const float* __restrict__ s_sh, const float* __restrict__ c_buf,
    const void* __restrict__ gv2, const void* __restrict__ bv2,
    u16* __restrict__ opbf, const int* __restrict__ dtf)
{
  const int f = dtf[0];
  int bi = blockIdx.x;
  int b = bi / 416, i = bi - b * 416;
  int g = i % 104, rq = i / 104;
  int tid = threadIdx.x;
  long obase = ((long)b * 104 + g) * 24 * 768;
#pragma unroll
  for (int it = 0; it < 3; ++it) {
    int d = tid + it * 256;
    int h = d >> 7, dh = d & 127;
    float o = bf2f(O[obase + (long)(h * 4 + rq) * 768 + d]);
    float ssh = s_sh[((long)b * 6 + h) * 416 + i];
    float val = gld(gv2, d, f) * (o - ssh) + gld(bv2, d, f)
              + c_buf[(((long)b * 6 + h) * 416 + i) * 128 + dh];
    opbf[((long)b * 416 + i) * 768 + d] = f2bf(val);
  }
}

// ---------------------------------------------------------------- host ------
static void launch_gemm(const void* A, const void* B, float* Cf, u16* Cb, int obf,
                        int M, int N, int K, int lda, int ldb, int ldc,
                        long sAo, long sAi, int adiv, long sBo, long sBi, int bdiv,
                        long sC, int zoff, int Z, int btrans, float alpha,
                        const int* dtf, int aSel, int bSel, hipStream_t st)
{
  dim3 grid((M + 63) / 64, (N + 63) / 64, Z);
  gemm_bf16<<<grid, dim3(256), 0, st>>>(A, B, Cf, Cb, obf, M, N, K, lda, ldb, ldc,
                                        sAo, sAi, adiv, sBo, sBi, bdiv,
                                        sC, zoff, btrans, alpha, dtf, aSel, bSel);
}

extern "C" void kernel_launch(void* const* d_in, const int* in_sizes, int n_in,
                              void* d_out, int out_size, void* d_ws, size_t ws_size,
                              hipStream_t stream)
{
  (void)in_sizes; (void)n_in;
  const void* x   = d_in[0];
  const void* ctx = d_in[1];
  const void* Wq  = d_in[2];
  const void* gq  = d_in[3];
  const void* bq  = d_in[4];
  const void* Wk  = d_in[5];
  const void* gk  = d_in[6];
  const void* bk  = d_in[7];
  const void* Wv  = d_in[8];
  const void* gv1 = d_in[9];
  const void* bv1 = d_in[10];
  const void* Wcv = d_in[11];
  const void* gv2 = d_in[12];
  const void* bv2 = d_in[13];
  const void* Wo  = d_in[14];
  const void* go  = d_in[15];
  const void* bo  = d_in[16];

  // -------- workspace layout --------
  const size_t SZ_FLAG = 256;
  const size_t SZ_QBF  = 2555904;    // 1664x768 bf16 (reused as final-GEMM scratch)
  const size_t SZ_KBF  = 1579008;    // 1028x768 bf16
  const size_t SZ_MID  = 13684736;   // WqT/WkT (pre-mid) -> midbf -> simf -> c_buf+Tb16/WoT
  const size_t SZ_MM   = 1703936;    // Mmat; later (+WB+MIDI+PIM): Obf 15.34MB
  const size_t SZ_WB   = 26624;
  const size_t SZ_MIDI = 13684736;
  const size_t SZ_PIM  = 427648;
  const size_t SZ_ABF  = 5271552;    // xb -> WvT (spans ABF+A2) -> Abf -> opbf
  const size_t SZ_A2   = 5271552;
  const size_t SZ_SSH  = 39936;
  const size_t SZ_CB   = 1579008;    // ctx bf16 copy (persistent)
  const size_t REQUIRED = SZ_FLAG + SZ_QBF + SZ_KBF + SZ_MID + SZ_MM + SZ_WB +
                          SZ_MIDI + SZ_PIM + SZ_ABF + SZ_A2 + SZ_SSH + SZ_CB;  // 45,824,896

  if (ws_size < REQUIRED) {  // diagnostic: report ws_size in MB via output
    fill_k<<<(out_size + 255) / 256, 256, 0, stream>>>((u16*)d_out, (float)(ws_size >> 20), out_size);
    return;
  }

  char* p = (char*)d_ws;
  int*   dtf   = (int*)  p;                 p += SZ_FLAG;
  u16*   qbf   = (u16*)  p;                 p += SZ_QBF;
  u16*   kbf   = (u16*)  p;                 p += SZ_KBF;
  char*  midrg = p;                         p += SZ_MID;
  char*  mmrg  = p;                         p += SZ_MM;
  float* wbar  = (float*)p;                 p += SZ_WB;
  u16*   midi  = (u16*)  p;                 p += SZ_MIDI;
  float* pim   = (float*)p;                 p += SZ_PIM;
  char*  abfrg = p;                         p += SZ_ABF;
  u16*   A2bf  = (u16*)  p;                 p += SZ_A2;
  float* s_sh  = (float*)p;                 p += SZ_SSH;
  u16*   cb    = (u16*)  p;                 p += SZ_CB;

  u16*   WqT   = (u16*)midrg;               // live: trans .. q GEMM (1.18MB)
  u16*   WkT   = (u16*)midrg;               // live: trans .. k GEMM
  u16*   midbf = (u16*)midrg;               // live: mid GEMM .. stats_k
  float* simf  = (float*)midrg;             // live: sim GEMM .. softmax (10.27MB)
  float* c_buf = (float*)midrg;             // live: c GEMM .. combine (5.11MB)
  u16*   Tb16  = (u16*)(midrg + 5111808);   // live: T GEMM .. O GEMM (1.28MB)
  u16*   WoT   = (u16*)(midrg + 5111808);   // live: trans (post-O) .. final GEMM (1.18MB)
  float* Mmat  = (float*)mmrg;              // live: gram .. stats_k
  u16*   Obf   = (u16*)mmrg;                // live: O GEMM .. combine (15.34MB over MM..PIM)
  u16*   xb    = (u16*)abfrg;               // live: conv .. q GEMM (2.56MB)
  u16*   WvT   = (u16*)abfrg;               // live: trans .. mid GEMM (10.22MB over ABF+A2)
  u16*   Abf   = (u16*)abfrg;               // live: softmax .. c GEMM
  u16*   opbf  = (u16*)abfrg;               // live: combine .. final GEMM

  probe_k<<<1, 256, 0, stream>>>((const u32*)x, dtf);

  // ---- prep: bf16 copies / transposes ----
  convb_k<<<(1277952 / 8 + 255) / 256, 256, 0, stream>>>(x, xb, 1277952, dtf);
  convb_k<<<(789504 / 8 + 255) / 256, 256, 0, stream>>>(ctx, cb, 789504, dtf);
  transb_k<<<dim3(24, 24), 256, 0, stream>>>(Wq, WqT, 768, 768, dtf);

  // q = LN(x @ Wq) : btrans, pure bf16
  launch_gemm(xb, WqT, nullptr, qbf, 1, 1664, 768, 768, 768, 768, 768,
              0, 0, 1, 0, 0, 1, 0, 0, 1, 1, 1.f, dtf, 0, 0, stream);
  ln_rows<<<1664, 256, 0, stream>>>(qbf, gq, bq, qbf, 768, dtf, 0);

  transb_k<<<dim3(24, 24), 256, 0, stream>>>(Wk, WkT, 768, 768, dtf);
  // k = LN(ctx @ Wk)
  launch_gemm(cb, WkT, nullptr, kbf, 1, 1028, 768, 768, 768, 768, 768,
              0, 0, 1, 0, 0, 1, 0, 0, 1, 1, 1.f, dtf, 0, 0, stream);
  ln_rows<<<1028, 256, 0, stream>>>(kbf, gk, bk, kbf, 768, dtf, 0);

  transb_k<<<dim3(208, 24), 256, 0, stream>>>(Wv, WvT, 768, 6656, dtf);
  // mid = LN(ctx @ Wv)
  launch_gemm(cb, WvT, nullptr, midbf, 1, 1028, 6656, 768, 768, 768, 6656,
              0, 0, 1, 0, 0, 1, 0, 0, 1, 1, 1.f, dtf, 0, 0, stream);
  ln_rows<<<1028, 256, 0, stream>>>(midbf, gv1, bv1, midbf, 6656, dtf, 0);

  // Gram: M[g] = Wconv[g] @ Wconv[g]^T / 768   (z=104, flag loads)
  launch_gemm(Wcv, Wcv, Mmat, nullptr, 0, 64, 64, 768, 768, 768, 64,
              49152, 0, 1, 49152, 0, 1, 4096, 0, 104, 1, 1.f / 768.f, dtf, 1, 1, stream);
  wbar_k<<<1664, 256, 0, stream>>>(Wcv, wbar, dtf);
  stats_k<<<dim3(104, 17), 256, 0, stream>>>(midbf, Mmat, wbar, midi, pim);

  // sim = scale^2 * q @ k^T   (z = b*6+h, btrans, fp32 out)
  launch_gemm(qbf, kbf, simf, nullptr, 0, 416, 257, 128, 768, 768, 257,
              319488, 128, 6, 197376, 128, 6, 106912, 0, 24, 1,
              0.08838834764831845f, dtf, 0, 0, stream);
  softmax_k<<<dim3(24, 104), 256, 0, stream>>>(simf, pim, Abf, A2bf, s_sh);

  // c = A @ ctx_head   (z = b*6+h; B = cb bf16)
  launch_gemm(Abf, cb, c_buf, nullptr, 0, 416, 128, 257, 264, 768, 128,
              109824, 0, 1, 197376, 128, 6, 53248, 0, 24, 0, 1.f, dtf, 0, 0, stream);
  // T = A2 @ midi      (z = b*104+g)
  launch_gemm(A2bf, midi, nullptr, Tb16, 1, 24, 64, 257, 264, 64, 64,
              6336, 0, 1, 16448, 0, 1, 1536, 0, 416, 0, 1.f, dtf, 0, 0, stream);
  // O = T @ Wconv[g]   (z = b*104+g, flag B loads)
  launch_gemm(Tb16, Wcv, nullptr, Obf, 1, 24, 768, 64, 64, 768, 768,
              1536, 0, 1, 0, 49152, 104, 18432, 0, 416, 0, 1.f, dtf, 0, 1, stream);

  transb_k<<<dim3(24, 24), 256, 0, stream>>>(Wo, WoT, 768, 768, dtf);  // Tb16 dead after O
  combine_k<<<1664, 256, 0, stream>>>(Obf, s_sh, c_buf, gv2, bv2, opbf, dtf);
  // out = LN(out_pre @ Wo): GEMM -> qbf scratch, LN -> d_out (flag dtype)
  launch_gemm(opbf, WoT, nullptr, qbf, 1, 1664, 768, 768, 768, 768, 768,
              0, 0, 1, 0, 0, 1, 0, 0, 1, 1, 1.f, dtf, 0, 0, stream);
  ln_rows<<<1664, 256, 0, stream>>>(qbf, go, bo, d_out, 768, dtf, 1);
}

// Round 9
// 418.938 us; speedup vs baseline: 2.1031x; 1.0161x over previous
//
#include <hip/hip_runtime.h>

// SubjBasisGenerator fused pipeline. B=4 NQ=416 NC=257 D=768 H=6 DH=128 G=104 R=4 LORA=64
// R9: stats_k (55us, LDS/barrier-bound, 0.88 GFLOP at 10x overhead) replaced by
// MFMA route: Gram -> bf16, batched Y = mid_g @ M[g] GEMM (2 chunks of 514 rows,
// Y-chunk 6.8MB in dead ABF+A2 span), thin stats2_k (1 wave/row).
//
// Algebra: the grouped-conv+LN v-path decomposes exactly (no (B,G,NC,768) tensor):
//   sum_j A_j v_j = gv2*( (sum_j A_j inv_j mid_j)@Wconv[g] - sum_j A_j inv_j mu_j )
//                   + bv2 + (A @ ctx)
//   q2[b,g,j] = mid^T M[g] mid = mid . (M[g] @ mid),  M[g] = Wconv[g]Wconv[g]^T/768

typedef unsigned short u16;
typedef unsigned int   u32;
typedef __attribute__((ext_vector_type(4))) float f32x4;
typedef __attribute__((ext_vector_type(4))) u32   u32x4;
typedef __attribute__((ext_vector_type(8))) short bf16x8;

__device__ __forceinline__ float bf2f(u16 v) { return __uint_as_float(((u32)v) << 16); }
__device__ __forceinline__ u16 f2bf(float f) {
  u32 u = __float_as_uint(f);
  u32 r = u + 0x7fffu + ((u >> 16) & 1u);  // RNE
  return (u16)(r >> 16);
}
__device__ __forceinline__ float gld(const void* p, long idx, int f32) {
  return f32 ? ((const float*)p)[idx] : bf2f(((const u16*)p)[idx]);
}

// ------------------------------------------------------------ dtype probe ---
__global__ __launch_bounds__(256) void probe_k(const u32* __restrict__ xw, int* __restrict__ flag) {
  int tid = threadIdx.x, c = 0;
  for (int i = tid; i < 4096; i += 256) {
    u16 lo = (u16)(xw[i] & 0xffffu);
    float a = fabsf(bf2f(lo));
    if (lo == 0 || (a >= 1e-3f && a <= 32.f)) ++c;
  }
#pragma unroll
  for (int o = 32; o; o >>= 1) c += __shfl_xor(c, o, 64);
  __shared__ int r[4];
  if ((tid & 63) == 0) r[tid >> 6] = c;
  __syncthreads();
  if (tid == 0) flag[0] = (r[0] + r[1] + r[2] + r[3] >= 2048) ? 0 : 1;  // 1 = fp32
}

// ------------------------------------------------------------ diag fill -----
__global__ __launch_bounds__(256) void fill_k(u16* p, float v, int n) {
  int i = blockIdx.x * 256 + threadIdx.x;
  if (i < n) p[i] = f2bf(v);
}

// ------------------------------------------------------- ext -> bf16 copy ---
__global__ __launch_bounds__(256) void convb_k(const void* __restrict__ in, u16* __restrict__ out,
                                               int n, const int* __restrict__ dtf) {
  const int f = dtf[0];
  int i = (blockIdx.x * 256 + threadIdx.x) * 8;
  if (i + 8 <= n) {
    if (f) {
      const float* ip = (const float*)in + i;
      f32x4 a = *(const f32x4*)ip, b = *(const f32x4*)(ip + 4);
      u32x4 q = { (u32)f2bf(a.x) | ((u32)f2bf(a.y) << 16),
                  (u32)f2bf(a.z) | ((u32)f2bf(a.w) << 16),
                  (u32)f2bf(b.x) | ((u32)f2bf(b.y) << 16),
                  (u32)f2bf(b.z) | ((u32)f2bf(b.w) << 16) };
      *(u32x4*)(out + i) = q;
    } else {
      *(u32x4*)(out + i) = *(const u32x4*)((const u16*)in + i);
    }
  } else {
    for (; i < n; ++i) out[i] = f2bf(gld(in, i, f));
  }
}

// ------------------------------------- ext [K,N] -> bf16 [N,K] transpose ----
__global__ __launch_bounds__(256) void transb_k(const void* __restrict__ in, u16* __restrict__ out,
                                                int K, int N, const int* __restrict__ dtf) {
  const int f = dtf[0];
  __shared__ float s[32][33];
  int n0 = blockIdx.x * 32, k0 = blockIdx.y * 32;
  int tx = threadIdx.x & 31, ty = threadIdx.x >> 5;  // 32 x 8
#pragma unroll
  for (int i = 0; i < 32; i += 8) {
    int k = k0 + ty + i, n = n0 + tx;
    float v = 0.f;
    if (k < K && n < N) v = gld(in, (long)k * N + n, f);
    s[ty + i][tx] = v;
  }
  __syncthreads();
#pragma unroll
  for (int i = 0; i < 32; i += 8) {
    int n = n0 + ty + i, k = k0 + tx;
    if (n < N && k < K) out[(long)n * K + k] = f2bf(s[tx][ty + i]);
  }
}

// ---------------------------------------------------------------- GEMM ------
// C = alpha*(A@B) (or A@B^T if btrans). aSel/bSel=1: operand follows dtype flag;
// 0: always-bf16 internal. Batch: zg = blockIdx.z + zoff;
//   aoff=(zg/adiv)*sAo+(zg%adiv)*sAi; boff=(zg/bdiv)*sBo+(zg%bdiv)*sBi;
//   C += blockIdx.z * sC. N-bounds guarded. 64x64 tile, BK=32, 4 waves,
// 2x2 mfma_f32_16x16x32_bf16 per wave.
#define LDS_S 40

__global__ __launch_bounds__(256) void gemm_bf16(
    const void* __restrict__ A, const void* __restrict__ B,
    float* __restrict__ Cf, u16* __restrict__ Cb, int obf,
    int M, int N, int K, int lda, int ldb, int ldc,
    long sAo, long sAi, int adiv, long sBo, long sBi, int bdiv,
    long sC, int zoff, int btrans, float alpha,
    const int* __restrict__ dtf, int aSel, int bSel)
{
  const int f = dtf[0];
  const int af32 = aSel & f, bf32 = bSel & f;
  const int zl = blockIdx.z, zg = zl + zoff;
  const long aoff = (long)(zg / adiv) * sAo + (long)(zg % adiv) * sAi;
  const long boff = (long)(zg / bdiv) * sBo + (long)(zg % bdiv) * sBi;
  const u16*   A16 = (const u16*)A + aoff;
  const float* A32 = (const float*)A + aoff;
  const u16*   B16 = (const u16*)B + boff;
  const float* B32 = (const float*)B + boff;

  __shared__ __attribute__((aligned(16))) u16 As[64 * LDS_S];
  __shared__ __attribute__((aligned(16))) u16 Bs[64 * LDS_S];

  const int tid = threadIdx.x;
  const int lane = tid & 63, wave = tid >> 6;
  const int m0 = blockIdx.x * 64, n0 = blockIdx.y * 64;
  const int wm = (wave >> 1) * 32, wn = (wave & 1) * 32;
  const int fm = lane & 15, fq = lane >> 4;

  const int ar = tid >> 2, ak = (tid & 3) * 8;   // A staging: row, k-offset
  const int bk = tid >> 3, bn = (tid & 7) * 8;   // B staging (non-trans path)

  f32x4 acc[2][2];
  const f32x4 zero4 = {0.f, 0.f, 0.f, 0.f};
#pragma unroll
  for (int a_ = 0; a_ < 2; ++a_)
#pragma unroll
    for (int b_ = 0; b_ < 2; ++b_) acc[a_][b_] = zero4;

  for (int k0 = 0; k0 < K; k0 += 32) {
    // ---- stage A tile (64 x 32) ----
    {
      int gm = m0 + ar, gk = k0 + ak;
      long idx = (long)gm * lda + gk;
      if (gm < M && gk + 8 <= K) {
        if (af32) {
          f32x4 u = *(const f32x4*)(A32 + idx), v = *(const f32x4*)(A32 + idx + 4);
          u32x4 q = { (u32)f2bf(u.x) | ((u32)f2bf(u.y) << 16),
                      (u32)f2bf(u.z) | ((u32)f2bf(u.w) << 16),
                      (u32)f2bf(v.x) | ((u32)f2bf(v.y) << 16),
                      (u32)f2bf(v.z) | ((u32)f2bf(v.w) << 16) };
          *(u32x4*)&As[ar * LDS_S + ak] = q;
        } else {
          *(u32x4*)&As[ar * LDS_S + ak] = *(const u32x4*)(A16 + idx);
        }
      } else {
#pragma unroll
        for (int e = 0; e < 8; ++e) {
          u16 v = 0;
          if (gm < M && gk + e < K) v = f2bf(gld(A, aoff + idx + e, af32));
          As[ar * LDS_S + ak + e] = v;
        }
      }
    }
    // ---- stage B tile as Bs[n][k] (64 x 32) ----
    if (btrans) {
      int gn = n0 + ar, gk = k0 + ak;
      long idx = (long)gn * ldb + gk;
      if (gn < N && gk + 8 <= K) {
        if (bf32) {
          f32x4 u = *(const f32x4*)(B32 + idx), v = *(const f32x4*)(B32 + idx + 4);
          u32x4 q = { (u32)f2bf(u.x) | ((u32)f2bf(u.y) << 16),
                      (u32)f2bf(u.z) | ((u32)f2bf(u.w) << 16),
                      (u32)f2bf(v.x) | ((u32)f2bf(v.y) << 16),
                      (u32)f2bf(v.z) | ((u32)f2bf(v.w) << 16) };
          *(u32x4*)&Bs[ar * LDS_S + ak] = q;
        } else {
          *(u32x4*)&Bs[ar * LDS_S + ak] = *(const u32x4*)(B16 + idx);
        }
      } else {
#pragma unroll
        for (int e = 0; e < 8; ++e) {
          u16 v = 0;
          if (gn < N && gk + e < K) v = f2bf(gld(B, boff + idx + e, bf32));
          Bs[ar * LDS_S + ak + e] = v;
        }
      }
    } else {
      int gk = k0 + bk;
      long idx = (long)gk * ldb + n0 + bn;
      u16 tmp[8];
      if (gk < K) {
        if (bf32) {
          f32x4 u = *(const f32x4*)(B32 + idx), v = *(const f32x4*)(B32 + idx + 4);
          tmp[0] = f2bf(u.x); tmp[1] = f2bf(u.y); tmp[2] = f2bf(u.z); tmp[3] = f2bf(u.w);
          tmp[4] = f2bf(v.x); tmp[5] = f2bf(v.y); tmp[6] = f2bf(v.z); tmp[7] = f2bf(v.w);
        } else {
          u32x4 v = *(const u32x4*)(B16 + idx);
          tmp[0] = (u16)(v.x & 0xffff); tmp[1] = (u16)(v.x >> 16);
          tmp[2] = (u16)(v.y & 0xffff); tmp[3] = (u16)(v.y >> 16);
          tmp[4] = (u16)(v.z & 0xffff); tmp[5] = (u16)(v.z >> 16);
          tmp[6] = (u16)(v.w & 0xffff); tmp[7] = (u16)(v.w >> 16);
        }
      } else {
#pragma unroll
        for (int e = 0; e < 8; ++e) tmp[e] = 0;
      }
      int rot = tid & 7;  // spread LDS bank writes
#pragma unroll
      for (int e = 0; e < 8; ++e) {
        int ee = (e + rot) & 7;
        Bs[(bn + ee) * LDS_S + bk] = tmp[ee];
      }
    }
    __syncthreads();
    {
      bf16x8 fa[2], fb[2];
      fa[0] = *(const bf16x8*)&As[(wm +      fm) * LDS_S + fq * 8];
      fa[1] = *(const bf16x8*)&As[(wm + 16 + fm) * LDS_S + fq * 8];
      fb[0] = *(const bf16x8*)&Bs[(wn +      fm) * LDS_S + fq * 8];
      fb[1] = *(const bf16x8*)&Bs[(wn + 16 + fm) * LDS_S + fq * 8];
#pragma unroll
      for (int mt = 0; mt < 2; ++mt)
#pragma unroll
        for (int nt = 0; nt < 2; ++nt)
          acc[mt][nt] = __builtin_amdgcn_mfma_f32_16x16x32_bf16(fa[mt], fb[nt], acc[mt][nt], 0, 0, 0);
    }
    __syncthreads();
  }
  // epilogue: C/D layout col=lane&15, row=(lane>>4)*4+reg (m89-verified)
#pragma unroll
  for (int mt = 0; mt < 2; ++mt)
#pragma unroll
    for (int nt = 0; nt < 2; ++nt)
#pragma unroll
      for (int rr = 0; rr < 4; ++rr) {
        int gm = m0 + wm + mt * 16 + fq * 4 + rr;
        int gn = n0 + wn + nt * 16 + fm;
        if (gm < M && gn < N) {
          float v = alpha * acc[mt][nt][rr];
          if (obf) Cb[(long)zl * sC + (long)gm * ldc + gn] = f2bf(v);
          else     Cf[(long)zl * sC + (long)gm * ldc + gn] = v;
        }
      }
}

// ------------------------------------------------------------- row LN -------
// 8-wide vectorized. N must be a multiple of 8 (768 / 6656 are).
__global__ __launch_bounds__(256) void ln_rows(
    const u16* __restrict__ in, const void* __restrict__ g, const void* __restrict__ b,
    void* __restrict__ out, int N, const int* __restrict__ dtf, int isfinal)
{
  const int f = dtf[0];
  long row = blockIdx.x;
  const u16* ip = in + row * N;
  int tid = threadIdx.x, lane = tid & 63, wave = tid >> 6;
  const int nv = N >> 3;
  float s1 = 0.f, s2 = 0.f;
  for (int c8 = tid; c8 < nv; c8 += 256) {
    u32x4 v = *(const u32x4*)(ip + c8 * 8);
    float e0 = bf2f((u16)(v.x & 0xffff)), e1 = bf2f((u16)(v.x >> 16));
    float e2 = bf2f((u16)(v.y & 0xffff)), e3 = bf2f((u16)(v.y >> 16));
    float e4 = bf2f((u16)(v.z & 0xffff)), e5 = bf2f((u16)(v.z >> 16));
    float e6 = bf2f((u16)(v.w & 0xffff)), e7 = bf2f((u16)(v.w >> 16));
    s1 += ((e0 + e1) + (e2 + e3)) + ((e4 + e5) + (e6 + e7));
    s2 += ((e0*e0 + e1*e1) + (e2*e2 + e3*e3)) + ((e4*e4 + e5*e5) + (e6*e6 + e7*e7));
  }
#pragma unroll
  for (int o = 32; o; o >>= 1) { s1 += __shfl_xor(s1, o, 64); s2 += __shfl_xor(s2, o, 64); }
  __shared__ float red[8];
  if (lane == 0) { red[wave] = s1; red[4 + wave] = s2; }
  __syncthreads();
  s1 = red[0] + red[1] + red[2] + red[3];
  s2 = red[4] + red[5] + red[6] + red[7];
  float mean = s1 / N;
  float var = s2 / N - mean * mean;
  float rstd = rsqrtf(fmaxf(var, 0.f) + 1e-5f);
  for (int c8 = tid; c8 < nv; c8 += 256) {
    int c = c8 * 8;
    u32x4 v = *(const u32x4*)(ip + c);
    float e[8];
    e[0] = bf2f((u16)(v.x & 0xffff)); e[1] = bf2f((u16)(v.x >> 16));
    e[2] = bf2f((u16)(v.y & 0xffff)); e[3] = bf2f((u16)(v.y >> 16));
    e[4] = bf2f((u16)(v.z & 0xffff)); e[5] = bf2f((u16)(v.z >> 16));
    e[6] = bf2f((u16)(v.w & 0xffff)); e[7] = bf2f((u16)(v.w >> 16));
    float gg[8], bb[8];
    if (f) {
      const float* gp = (const float*)g + c; const float* bp = (const float*)b + c;
      f32x4 g0 = *(const f32x4*)gp, g1 = *(const f32x4*)(gp + 4);
      f32x4 b0 = *(const f32x4*)bp, b1 = *(const f32x4*)(bp + 4);
      gg[0]=g0.x; gg[1]=g0.y; gg[2]=g0.z; gg[3]=g0.w; gg[4]=g1.x; gg[5]=g1.y; gg[6]=g1.z; gg[7]=g1.w;
      bb[0]=b0.x; bb[1]=b0.y; bb[2]=b0.z; bb[3]=b0.w; bb[4]=b1.x; bb[5]=b1.y; bb[6]=b1.z; bb[7]=b1.w;
    } else {
      u32x4 gv = *(const u32x4*)((const u16*)g + c);
      u32x4 bv = *(const u32x4*)((const u16*)b + c);
      gg[0]=bf2f((u16)(gv.x&0xffff)); gg[1]=bf2f((u16)(gv.x>>16));
      gg[2]=bf2f((u16)(gv.y&0xffff)); gg[3]=bf2f((u16)(gv.y>>16));
      gg[4]=bf2f((u16)(gv.z&0xffff)); gg[5]=bf2f((u16)(gv.z>>16));
      gg[6]=bf2f((u16)(gv.w&0xffff)); gg[7]=bf2f((u16)(gv.w>>16));
      bb[0]=bf2f((u16)(bv.x&0xffff)); bb[1]=bf2f((u16)(bv.x>>16));
      bb[2]=bf2f((u16)(bv.y&0xffff)); bb[3]=bf2f((u16)(bv.y>>16));
      bb[4]=bf2f((u16)(bv.z&0xffff)); bb[5]=bf2f((u16)(bv.z>>16));
      bb[6]=bf2f((u16)(bv.w&0xffff)); bb[7]=bf2f((u16)(bv.w>>16));
    }
    float o_[8];
#pragma unroll
    for (int e2i = 0; e2i < 8; ++e2i) o_[e2i] = (e[e2i] - mean) * rstd * gg[e2i] + bb[e2i];
    if (isfinal && f) {
      float* op = (float*)out + row * N + c;
      f32x4 o0 = {o_[0], o_[1], o_[2], o_[3]}, o1 = {o_[4], o_[5], o_[6], o_[7]};
      *(f32x4*)op = o0; *(f32x4*)(op + 4) = o1;
    } else {
      u32x4 q = { (u32)f2bf(o_[0]) | ((u32)f2bf(o_[1]) << 16),
                  (u32)f2bf(o_[2]) | ((u32)f2bf(o_[3]) << 16),
                  (u32)f2bf(o_[4]) | ((u32)f2bf(o_[5]) << 16),
                  (u32)f2bf(o_[6]) | ((u32)f2bf(o_[7]) << 16) };
      *(u32x4*)((u16*)out + row * N + c) = q;
    }
  }
}

// ------------------------------------------------------------- wbar ---------
// one wave per (g,l) row. grid 1664 x 4 waves = 6656 rows.
__global__ __launch_bounds__(256) void wbar_k(const void* __restrict__ Wconv,
                                              float* __restrict__ wbar,
                                              const int* __restrict__ dtf)
{
  const int f = dtf[0];
  int r = blockIdx.x * 4 + (threadIdx.x >> 6);   // row 0..6655 = g*64+l
  int lane = threadIdx.x & 63;
  long base = (long)r * 768;
  float s = 0.f;
  for (int c = lane; c < 768; c += 64) s += gld(Wconv, base + c, f);
#pragma unroll
  for (int o = 32; o; o >>= 1) s += __shfl_xor(s, o, 64);
  if (lane == 0) wbar[r] = s * (1.f / 768.f);
}

// ------------------------------------------------------------- stats2 -------
// R9: per (g, chunk-row): read mid row + Y row (Y = mid @ M[g], bf16 from GEMM),
// two shuffle reduces -> inv, write midi bf16 + pim. 1 wave/row.
__global__ __launch_bounds__(256) void stats2_k(
    const u16* __restrict__ midbf, const u16* __restrict__ Y, const float* __restrict__ wbar,
    u16* __restrict__ midi, float* __restrict__ pim, int c)
{
  int g = blockIdx.y;
  int r = blockIdx.x * 4 + (threadIdx.x >> 6);
  if (r >= 514) return;
  int lane = threadIdx.x & 63;
  int R = c * 514 + r;
  int b = R / 257, j = R - b * 257;
  float m = bf2f(midbf[(long)R * 6656 + g * 64 + lane]);
  float y = bf2f(Y[((long)g * 514 + r) * 64 + lane]);
  float wb = wbar[g * 64 + lane];
  float mup = m * wb, q2p = m * y;
#pragma unroll
  for (int o = 32; o; o >>= 1) { mup += __shfl_xor(mup, o, 64); q2p += __shfl_xor(q2p, o, 64); }
  float var = q2p - mup * mup;
  float inv = rsqrtf(fmaxf(var, 0.f) + 1e-5f);
  long base = ((long)b * 104 + g) * 257 + j;
  midi[base * 64 + lane] = f2bf(inv * m);
  if (lane == 0) pim[base] = inv * mup;
}

// ------------------------------------------------------------- softmax ------
__global__ __launch_bounds__(256) void softmax_k(
    const float* __restrict__ simf, const float* __restrict__ pim,
    u16* __restrict__ Abf, u16* __restrict__ A2bf, float* __restrict__ s_sh)
{
  int bh = blockIdx.x;
  int b = bh / 6, h = bh - b * 6;
  int tid = threadIdx.x, lane = tid & 63, wave = tid >> 6;
  int i = blockIdx.y * 4 + wave;
  int g = i % 104, rq = i / 104;
  const float* sp_ = simf + ((long)bh * 416 + i) * 257;
  float s[5];
#pragma unroll
  for (int jc = 0; jc < 5; ++jc) {
    int j = jc * 64 + lane;
    s[jc] = (j < 257) ? sp_[j] : -1e30f;
  }
  float mx = -1e30f;
#pragma unroll
  for (int jc = 0; jc < 5; ++jc) mx = fmaxf(mx, s[jc]);
#pragma unroll
  for (int o = 32; o; o >>= 1) mx = fmaxf(mx, __shfl_xor(mx, o, 64));
  float p[5], sum = 0.f, sp = 0.f;
  long pimb = ((long)b * 104 + g) * 257;
#pragma unroll
  for (int jc = 0; jc < 5; ++jc) {
    int j = jc * 64 + lane;
    float pv = 0.f;
    if (j < 257) { pv = __expf(s[jc] - mx); sp = fmaf(pv, pim[pimb + j], sp); }
    p[jc] = pv; sum += pv;
  }
#pragma unroll
  for (int o = 32; o; o >>= 1) { sum += __shfl_xor(sum, o, 64); sp += __shfl_xor(sp, o, 64); }
  float rs = 1.f / sum;
  long arow  = ((long)bh * 416 + i) * 264;
  long a2row = (((long)b * 104 + g) * 24 + h * 4 + rq) * 264;
#pragma unroll
  for (int jc = 0; jc < 5; ++jc) {
    int j = jc * 64 + lane;
    if (j < 257) { u16 pb = f2bf(p[jc] * rs); Abf[arow + j] = pb; A2bf[a2row + j] = pb; }
    else if (j < 264) { Abf[arow + j] = 0; A2bf[a2row + j] = 0; }
  }
  if (lane == 0) s_sh[(long)bh * 416 + i] = sp * rs;
}

// ------------------------------------------------------------- combine ------
__global__ __launch_bounds__(256) void combine_k(
    const u16* __restrict__ O, const float* __restrict__ s_sh, const float* __restrict__ c_buf,
    const void* __restrict__ gv2, const void* __restrict__ bv2,
    u16* __restrict__ opbf, const int* __restrict__ dtf)
{
  const int f = dtf[0];
  int bi = blockIdx.x;
  int b = bi / 416, i = bi - b * 416;
  int g = i % 104, rq = i / 104;
  int tid = threadIdx.x;
  long obase = ((long)b * 104 + g) * 24 * 768;
#pragma unroll
  for (int it = 0; it < 3; ++it) {
    int d = tid + it * 256;
    int h = d >> 7, dh = d & 127;
    float o = bf2f(O[obase + (long)(h * 4 + rq) * 768 + d]);
    float ssh = s_sh[((long)b * 6 + h) * 416 + i];
    float val = gld(gv2, d, f) * (o - ssh) + gld(bv2, d, f)
              + c_buf[(((long)b * 6 + h) * 416 + i) * 128 + dh];
    opbf[((long)b * 416 + i) * 768 + d] = f2bf(val);
  }
}

// ---------------------------------------------------------------- host ------
static void launch_gemm(const void* A, const void* B, float* Cf, u16* Cb, int obf,
                        int M, int N, int K, int lda, int ldb, int ldc,
                        long sAo, long sAi, int adiv, long sBo, long sBi, int bdiv,
                        long sC, int zoff, int Z, int btrans, float alpha,
                        const int* dtf, int aSel, int bSel, hipStream_t st)
{
  dim3 grid((M + 63) / 64, (N + 63) / 64, Z);
  gemm_bf16<<<grid, dim3(256), 0, st>>>(A, B, Cf, Cb, obf, M, N, K, lda, ldb, ldc,
                                        sAo, sAi, adiv, sBo, sBi, bdiv,
                                        sC, zoff, btrans, alpha, dtf, aSel, bSel);
}

extern "C" void kernel_launch(void* const* d_in, const int* in_sizes, int n_in,
                              void* d_out, int out_size, void* d_ws, size_t ws_size,
                              hipStream_t stream)
{
  (void)in_sizes; (void)n_in;
  const void* x   = d_in[0];
  const void* ctx = d_in[1];
  const void* Wq  = d_in[2];
  const void* gq  = d_in[3];
  const void* bq  = d_in[4];
  const void* Wk  = d_in[5];
  const void* gk  = d_in[6];
  const void* bk  = d_in[7];
  const void* Wv  = d_in[8];
  const void* gv1 = d_in[9];
  const void* bv1 = d_in[10];
  const void* Wcv = d_in[11];
  const void* gv2 = d_in[12];
  const void* bv2 = d_in[13];
  const void* Wo  = d_in[14];
  const void* go  = d_in[15];
  const void* bo  = d_in[16];

  // -------- workspace layout --------
  const size_t SZ_FLAG = 256;
  const size_t SZ_QBF  = 2555904;    // 1664x768 bf16 (reused as final-GEMM scratch)
  const size_t SZ_KBF  = 1579008;    // 1028x768 bf16
  const size_t SZ_MID  = 13684736;   // WqT/WkT (pre-mid) -> midbf -> simf -> c_buf+Tb16/WoT
  const size_t SZ_MM   = 1703936;    // Gram bf16 (852KB); later (+WB+MIDI+PIM): Obf 15.34MB
  const size_t SZ_WB   = 26624;
  const size_t SZ_MIDI = 13684736;
  const size_t SZ_PIM  = 427648;
  const size_t SZ_ABF  = 5271552;    // xb -> WvT (spans ABF+A2) -> Y chunks -> Abf -> opbf
  const size_t SZ_A2   = 5271552;
  const size_t SZ_SSH  = 39936;
  const size_t SZ_CB   = 1579008;    // ctx bf16 copy (persistent)
  const size_t REQUIRED = SZ_FLAG + SZ_QBF + SZ_KBF + SZ_MID + SZ_MM + SZ_WB +
                          SZ_MIDI + SZ_PIM + SZ_ABF + SZ_A2 + SZ_SSH + SZ_CB;  // 45,824,896

  if (ws_size < REQUIRED) {  // diagnostic: report ws_size in MB via output
    fill_k<<<(out_size + 255) / 256, 256, 0, stream>>>((u16*)d_out, (float)(ws_size >> 20), out_size);
    return;
  }

  char* p = (char*)d_ws;
  int*   dtf   = (int*)  p;                 p += SZ_FLAG;
  u16*   qbf   = (u16*)  p;                 p += SZ_QBF;
  u16*   kbf   = (u16*)  p;                 p += SZ_KBF;
  char*  midrg = p;                         p += SZ_MID;
  char*  mmrg  = p;                         p += SZ_MM;
  float* wbar  = (float*)p;                 p += SZ_WB;
  u16*   midi  = (u16*)  p;                 p += SZ_MIDI;
  float* pim   = (float*)p;                 p += SZ_PIM;
  char*  abfrg = p;                         p += SZ_ABF;
  u16*   A2bf  = (u16*)  p;                 p += SZ_A2;
  float* s_sh  = (float*)p;                 p += SZ_SSH;
  u16*   cb    = (u16*)  p;                 p += SZ_CB;

  u16*   WqT   = (u16*)midrg;               // live: trans .. q GEMM (1.18MB)
  u16*   WkT   = (u16*)midrg;               // live: trans .. k GEMM
  u16*   midbf = (u16*)midrg;               // live: mid GEMM .. stats2 (chunk 1)
  float* simf  = (float*)midrg;             // live: sim GEMM .. softmax (10.27MB)
  float* c_buf = (float*)midrg;             // live: c GEMM .. combine (5.11MB)
  u16*   Tb16  = (u16*)(midrg + 5111808);   // live: T GEMM .. O GEMM (1.28MB)
  u16*   WoT   = (u16*)(midrg + 5111808);   // live: trans (post-O) .. final GEMM (1.18MB)
  u16*   Gb    = (u16*)mmrg;                // Gram bf16 (852KB): gram .. Y GEMMs
  u16*   Obf   = (u16*)mmrg;                // live: O GEMM .. combine (15.34MB over MM..PIM)
  u16*   xb    = (u16*)abfrg;               // live: conv .. q GEMM (2.56MB)
  u16*   WvT   = (u16*)abfrg;               // live: trans .. mid GEMM (10.22MB over ABF+A2)
  u16*   Ybuf  = (u16*)abfrg;               // live: Y GEMM chunk .. stats2 chunk (6.84MB)
  u16*   Abf   = (u16*)abfrg;               // live: softmax .. c GEMM
  u16*   opbf  = (u16*)abfrg;               // live: combine .. final GEMM

  probe_k<<<1, 256, 0, stream>>>((const u32*)x, dtf);

  // ---- prep: bf16 copies / transposes ----
  convb_k<<<(1277952 / 8 + 255) / 256, 256, 0, stream>>>(x, xb, 1277952, dtf);
  convb_k<<<(789504 / 8 + 255) / 256, 256, 0, stream>>>(ctx, cb, 789504, dtf);
  transb_k<<<dim3(24, 24), 256, 0, stream>>>(Wq, WqT, 768, 768, dtf);

  // q = LN(x @ Wq) : btrans, pure bf16
  launch_gemm(xb, WqT, nullptr, qbf, 1, 1664, 768, 768, 768, 768, 768,
              0, 0, 1, 0, 0, 1, 0, 0, 1, 1, 1.f, dtf, 0, 0, stream);
  ln_rows<<<1664, 256, 0, stream>>>(qbf, gq, bq, qbf, 768, dtf, 0);

  transb_k<<<dim3(24, 24), 256, 0, stream>>>(Wk, WkT, 768, 768, dtf);
  // k = LN(ctx @ Wk)
  launch_gemm(cb, WkT, nullptr, kbf, 1, 1028, 768, 768, 768, 768, 768,
              0, 0, 1, 0, 0, 1, 0, 0, 1, 1, 1.f, dtf, 0, 0, stream);
  ln_rows<<<1028, 256, 0, stream>>>(kbf, gk, bk, kbf, 768, dtf, 0);

  transb_k<<<dim3(208, 24), 256, 0, stream>>>(Wv, WvT, 768, 6656, dtf);
  // mid = LN(ctx @ Wv)
  launch_gemm(cb, WvT, nullptr, midbf, 1, 1028, 6656, 768, 768, 768, 6656,
              0, 0, 1, 0, 0, 1, 0, 0, 1, 1, 1.f, dtf, 0, 0, stream);
  ln_rows<<<1028, 256, 0, stream>>>(midbf, gv1, bv1, midbf, 6656, dtf, 0);

  // Gram: M[g] = Wconv[g] @ Wconv[g]^T / 768  (z=104, flag loads, bf16 out)
  launch_gemm(Wcv, Wcv, nullptr, Gb, 1, 64, 64, 768, 768, 768, 64,
              49152, 0, 1, 49152, 0, 1, 4096, 0, 104, 1, 1.f / 768.f, dtf, 1, 1, stream);
  wbar_k<<<1664, 256, 0, stream>>>(Wcv, wbar, dtf);
  // stats via MFMA: Y = mid_g @ M[g] (symmetric -> btrans ok), 2 chunks of 514 rows
  for (int c = 0; c < 2; ++c) {
    launch_gemm(midbf + (long)c * 514 * 6656, Gb, nullptr, Ybuf, 1,
                514, 64, 64, 6656, 64, 64,
                0, 64, 104, 4096, 0, 1, 32896, 0, 104, 1, 1.f, dtf, 0, 0, stream);
    stats2_k<<<dim3(129, 104), 256, 0, stream>>>(midbf, Ybuf, wbar, midi, pim, c);
  }

  // sim = scale^2 * q @ k^T   (z = b*6+h, btrans, fp32 out)
  launch_gemm(qbf, kbf, simf, nullptr, 0, 416, 257, 128, 768, 768, 257,
              319488, 128, 6, 197376, 128, 6, 106912, 0, 24, 1,
              0.08838834764831845f, dtf, 0, 0, stream);
  softmax_k<<<dim3(24, 104), 256, 0, stream>>>(simf, pim, Abf, A2bf, s_sh);

  // c = A @ ctx_head   (z = b*6+h; B = cb bf16)
  launch_gemm(Abf, cb, c_buf, nullptr, 0, 416, 128, 257, 264, 768, 128,
              109824, 0, 1, 197376, 128, 6, 53248, 0, 24, 0, 1.f, dtf, 0, 0, stream);
  // T = A2 @ midi      (z = b*104+g)
  launch_gemm(A2bf, midi, nullptr, Tb16, 1, 24, 64, 257, 264, 64, 64,
              6336, 0, 1, 16448, 0, 1, 1536, 0, 416, 0, 1.f, dtf, 0, 0, stream);
  // O = T @ Wconv[g]   (z = b*104+g, flag B loads)
  launch_gemm(Tb16, Wcv, nullptr, Obf, 1, 24, 768, 64, 64, 768, 768,
              1536, 0, 1, 0, 49152, 104, 18432, 0, 416, 0, 1.f, dtf, 0, 1, stream);

  transb_k<<<dim3(24, 24), 256, 0, stream>>>(Wo, WoT, 768, 768, dtf);  // Tb16 dead after O
  combine_k<<<1664, 256, 0, stream>>>(Obf, s_sh, c_buf, gv2, bv2, opbf, dtf);
  // out = LN(out_pre @ Wo): GEMM -> qbf scratch, LN -> d_out (flag dtype)
  launch_gemm(opbf, WoT, nullptr, qbf, 1, 1664, 768, 768, 768, 768, 768,
              0, 0, 1, 0, 0, 1, 0, 0, 1, 1, 1.f, dtf, 0, 0, stream);
  ln_rows<<<1664, 256, 0, stream>>>(qbf, go, bo, d_out, 768, dtf, 1);
}

// Round 10
// 401.534 us; speedup vs baseline: 2.1943x; 1.0433x over previous
//
#include <hip/hip_runtime.h>

// SubjBasisGenerator fused pipeline. B=4 NQ=416 NC=257 D=768 H=6 DH=128 G=104 R=4 LORA=64
// R10: big row-major GEMMs (q/k/mid/final) moved to gemm128 — 128x128 tile,
// 4x4 MFMA acc/wave, global_load_lds width-16 async staging (m93->m97 ladder).
// R9 mid GEMM: 51us, MfmaUtil 8%, nothing saturated -> latency-bound 64^2 plateau.
//
// Algebra: the grouped-conv+LN v-path decomposes exactly (no (B,G,NC,768) tensor):
//   sum_j A_j v_j = gv2*( (sum_j A_j inv_j mid_j)@Wconv[g] - sum_j A_j inv_j mu_j )
//                   + bv2 + (A @ ctx)
//   q2[b,g,j] = mid^T M[g] mid = mid . (M[g] @ mid),  M[g] = Wconv[g]Wconv[g]^T/768

typedef unsigned short u16;
typedef unsigned int   u32;
typedef __attribute__((ext_vector_type(4))) float f32x4;
typedef __attribute__((ext_vector_type(4))) u32   u32x4;
typedef __attribute__((ext_vector_type(8))) short bf16x8;

__device__ __forceinline__ float bf2f(u16 v) { return __uint_as_float(((u32)v) << 16); }
__device__ __forceinline__ u16 f2bf(float f) {
  u32 u = __float_as_uint(f);
  u32 r = u + 0x7fffu + ((u >> 16) & 1u);  // RNE
  return (u16)(r >> 16);
}
__device__ __forceinline__ float gld(const void* p, long idx, int f32) {
  return f32 ? ((const float*)p)[idx] : bf2f(((const u16*)p)[idx]);
}

typedef const __attribute__((address_space(1))) u32 gas_u32;
typedef __attribute__((address_space(3))) u32 las_u32;

// async 16B/lane global->LDS; LDS dest = wave-uniform base + lane*16 (m97).
__device__ __forceinline__ void stage16(const u16* g, u16* lbase, int lane) {
#if __has_builtin(__builtin_amdgcn_global_load_lds)
  (void)lane;
  __builtin_amdgcn_global_load_lds((gas_u32*)g, (las_u32*)lbase, 16, 0, 0);
#else
  *(u32x4*)(lbase + lane * 8) = *(const u32x4*)g;
#endif
}

// ------------------------------------------------------------ dtype probe ---
__global__ __launch_bounds__(256) void probe_k(const u32* __restrict__ xw, int* __restrict__ flag) {
  int tid = threadIdx.x, c = 0;
  for (int i = tid; i < 4096; i += 256) {
    u16 lo = (u16)(xw[i] & 0xffffu);
    float a = fabsf(bf2f(lo));
    if (lo == 0 || (a >= 1e-3f && a <= 32.f)) ++c;
  }
#pragma unroll
  for (int o = 32; o; o >>= 1) c += __shfl_xor(c, o, 64);
  __shared__ int r[4];
  if ((tid & 63) == 0) r[tid >> 6] = c;
  __syncthreads();
  if (tid == 0) flag[0] = (r[0] + r[1] + r[2] + r[3] >= 2048) ? 0 : 1;  // 1 = fp32
}

// ------------------------------------------------------------ diag fill -----
__global__ __launch_bounds__(256) void fill_k(u16* p, float v, int n) {
  int i = blockIdx.x * 256 + threadIdx.x;
  if (i < n) p[i] = f2bf(v);
}

// ------------------------------------------------------- ext -> bf16 copy ---
__global__ __launch_bounds__(256) void convb_k(const void* __restrict__ in, u16* __restrict__ out,
                                               int n, const int* __restrict__ dtf) {
  const int f = dtf[0];
  int i = (blockIdx.x * 256 + threadIdx.x) * 8;
  if (i + 8 <= n) {
    if (f) {
      const float* ip = (const float*)in + i;
      f32x4 a = *(const f32x4*)ip, b = *(const f32x4*)(ip + 4);
      u32x4 q = { (u32)f2bf(a.x) | ((u32)f2bf(a.y) << 16),
                  (u32)f2bf(a.z) | ((u32)f2bf(a.w) << 16),
                  (u32)f2bf(b.x) | ((u32)f2bf(b.y) << 16),
                  (u32)f2bf(b.z) | ((u32)f2bf(b.w) << 16) };
      *(u32x4*)(out + i) = q;
    } else {
      *(u32x4*)(out + i) = *(const u32x4*)((const u16*)in + i);
    }
  } else {
    for (; i < n; ++i) out[i] = f2bf(gld(in, i, f));
  }
}

// ------------------------------------- ext [K,N] -> bf16 [N,K] transpose ----
__global__ __launch_bounds__(256) void transb_k(const void* __restrict__ in, u16* __restrict__ out,
                                                int K, int N, const int* __restrict__ dtf) {
  const int f = dtf[0];
  __shared__ float s[32][33];
  int n0 = blockIdx.x * 32, k0 = blockIdx.y * 32;
  int tx = threadIdx.x & 31, ty = threadIdx.x >> 5;  // 32 x 8
#pragma unroll
  for (int i = 0; i < 32; i += 8) {
    int k = k0 + ty + i, n = n0 + tx;
    float v = 0.f;
    if (k < K && n < N) v = gld(in, (long)k * N + n, f);
    s[ty + i][tx] = v;
  }
  __syncthreads();
#pragma unroll
  for (int i = 0; i < 32; i += 8) {
    int n = n0 + ty + i, k = k0 + tx;
    if (n < N && k < K) out[(long)n * K + k] = f2bf(s[tx][ty + i]);
  }
}

// ------------------------------------------------------------- gemm128 ------
// C_bf16 = A_bf16[M,K] @ B_bf16[N,K]^T. Requires N%128==0, K%32==0; M-tail via
// row-clamped staging + guarded writes. 128x128 tile, BK=32, 4 waves each 64x64
// (4x4 mfma_f32_16x16x32_bf16). LDS unpadded [row][32] fed by stage16.
__global__ __launch_bounds__(256) void gemm128(
    const u16* __restrict__ A, const u16* __restrict__ B, u16* __restrict__ C,
    int M, int N, int K, int lda, int ldb, int ldc)
{
  __shared__ __attribute__((aligned(16))) u16 As[128 * 32];
  __shared__ __attribute__((aligned(16))) u16 Bs[128 * 32];
  const int tid = threadIdx.x, lane = tid & 63, wave = tid >> 6;
  const int m0 = blockIdx.x * 128, n0 = blockIdx.y * 128;
  const int wm = (wave >> 1) * 64, wn = (wave & 1) * 64;
  const int fm = lane & 15, fq = lane >> 4;

  // staging addresses: lane covers row (lane>>2), 16B chunk (lane&3)
  const int srow = lane >> 2, selem = (lane & 3) * 8;
  int ra1 = m0 + wave * 16 + srow;      if (ra1 > M - 1) ra1 = M - 1;
  int ra2 = m0 + 64 + wave * 16 + srow; if (ra2 > M - 1) ra2 = M - 1;
  const int rb1 = n0 + wave * 16 + srow;
  const int rb2 = n0 + 64 + wave * 16 + srow;
  const u16* pa1 = A + (long)ra1 * lda + selem;
  const u16* pa2 = A + (long)ra2 * lda + selem;
  const u16* pb1 = B + (long)rb1 * ldb + selem;
  const u16* pb2 = B + (long)rb2 * ldb + selem;
  u16* la1 = As + wave * 512;
  u16* la2 = As + 2048 + wave * 512;
  u16* lb1 = Bs + wave * 512;
  u16* lb2 = Bs + 2048 + wave * 512;

  f32x4 acc[4][4];
  const f32x4 zero4 = {0.f, 0.f, 0.f, 0.f};
#pragma unroll
  for (int a_ = 0; a_ < 4; ++a_)
#pragma unroll
    for (int b_ = 0; b_ < 4; ++b_) acc[a_][b_] = zero4;

  for (int k0 = 0; k0 < K; k0 += 32) {
    stage16(pa1, la1, lane);
    stage16(pa2, la2, lane);
    stage16(pb1, lb1, lane);
    stage16(pb2, lb2, lane);
    pa1 += 32; pa2 += 32; pb1 += 32; pb2 += 32;
    __syncthreads();   // compiler drains vmcnt before barrier
    bf16x8 fa[4], fb[4];
#pragma unroll
    for (int mt = 0; mt < 4; ++mt)
      fa[mt] = *(const bf16x8*)&As[(wm + mt * 16 + fm) * 32 + fq * 8];
#pragma unroll
    for (int nt = 0; nt < 4; ++nt)
      fb[nt] = *(const bf16x8*)&Bs[(wn + nt * 16 + fm) * 32 + fq * 8];
#pragma unroll
    for (int mt = 0; mt < 4; ++mt)
#pragma unroll
      for (int nt = 0; nt < 4; ++nt)
        acc[mt][nt] = __builtin_amdgcn_mfma_f32_16x16x32_bf16(fa[mt], fb[nt], acc[mt][nt], 0, 0, 0);
    __syncthreads();
  }
  // C/D layout: col=lane&15, row=(lane>>4)*4+reg (m89-verified)
#pragma unroll
  for (int mt = 0; mt < 4; ++mt)
#pragma unroll
    for (int nt = 0; nt < 4; ++nt)
#pragma unroll
      for (int rr = 0; rr < 4; ++rr) {
        int gm = m0 + wm + mt * 16 + fq * 4 + rr;
        int gn = n0 + wn + nt * 16 + fm;
        if (gm < M) C[(long)gm * ldc + gn] = f2bf(acc[mt][nt][rr]);
      }
}

// ---------------------------------------------------------------- GEMM ------
// (64x64 general kernel — batched / flag-dtype / fp32-out cases)
#define LDS_S 40

__global__ __launch_bounds__(256) void gemm_bf16(
    const void* __restrict__ A, const void* __restrict__ B,
    float* __restrict__ Cf, u16* __restrict__ Cb, int obf,
    int M, int N, int K, int lda, int ldb, int ldc,
    long sAo, long sAi, int adiv, long sBo, long sBi, int bdiv,
    long sC, int zoff, int btrans, float alpha,
    const int* __restrict__ dtf, int aSel, int bSel)
{
  const int f = dtf[0];
  const int af32 = aSel & f, bf32 = bSel & f;
  const int zl = blockIdx.z, zg = zl + zoff;
  const long aoff = (long)(zg / adiv) * sAo + (long)(zg % adiv) * sAi;
  const long boff = (long)(zg / bdiv) * sBo + (long)(zg % bdiv) * sBi;
  const u16*   A16 = (const u16*)A + aoff;
  const float* A32 = (const float*)A + aoff;
  const u16*   B16 = (const u16*)B + boff;
  const float* B32 = (const float*)B + boff;

  __shared__ __attribute__((aligned(16))) u16 As[64 * LDS_S];
  __shared__ __attribute__((aligned(16))) u16 Bs[64 * LDS_S];

  const int tid = threadIdx.x;
  const int lane = tid & 63, wave = tid >> 6;
  const int m0 = blockIdx.x * 64, n0 = blockIdx.y * 64;
  const int wm = (wave >> 1) * 32, wn = (wave & 1) * 32;
  const int fm = lane & 15, fq = lane >> 4;

  const int ar = tid >> 2, ak = (tid & 3) * 8;   // A staging: row, k-offset
  const int bk = tid >> 3, bn = (tid & 7) * 8;   // B staging (non-trans path)

  f32x4 acc[2][2];
  const f32x4 zero4 = {0.f, 0.f, 0.f, 0.f};
#pragma unroll
  for (int a_ = 0; a_ < 2; ++a_)
#pragma unroll
    for (int b_ = 0; b_ < 2; ++b_) acc[a_][b_] = zero4;

  for (int k0 = 0; k0 < K; k0 += 32) {
    // ---- stage A tile (64 x 32) ----
    {
      int gm = m0 + ar, gk = k0 + ak;
      long idx = (long)gm * lda + gk;
      if (gm < M && gk + 8 <= K) {
        if (af32) {
          f32x4 u = *(const f32x4*)(A32 + idx), v = *(const f32x4*)(A32 + idx + 4);
          u32x4 q = { (u32)f2bf(u.x) | ((u32)f2bf(u.y) << 16),
                      (u32)f2bf(u.z) | ((u32)f2bf(u.w) << 16),
                      (u32)f2bf(v.x) | ((u32)f2bf(v.y) << 16),
                      (u32)f2bf(v.z) | ((u32)f2bf(v.w) << 16) };
          *(u32x4*)&As[ar * LDS_S + ak] = q;
        } else {
          *(u32x4*)&As[ar * LDS_S + ak] = *(const u32x4*)(A16 + idx);
        }
      } else {
#pragma unroll
        for (int e = 0; e < 8; ++e) {
          u16 v = 0;
          if (gm < M && gk + e < K) v = f2bf(gld(A, aoff + idx + e, af32));
          As[ar * LDS_S + ak + e] = v;
        }
      }
    }
    // ---- stage B tile as Bs[n][k] (64 x 32) ----
    if (btrans) {
      int gn = n0 + ar, gk = k0 + ak;
      long idx = (long)gn * ldb + gk;
      if (gn < N && gk + 8 <= K) {
        if (bf32) {
          f32x4 u = *(const f32x4*)(B32 + idx), v = *(const f32x4*)(B32 + idx + 4);
          u32x4 q = { (u32)f2bf(u.x) | ((u32)f2bf(u.y) << 16),
                      (u32)f2bf(u.z) | ((u32)f2bf(u.w) << 16),
                      (u32)f2bf(v.x) | ((u32)f2bf(v.y) << 16),
                      (u32)f2bf(v.z) | ((u32)f2bf(v.w) << 16) };
          *(u32x4*)&Bs[ar * LDS_S + ak] = q;
        } else {
          *(u32x4*)&Bs[ar * LDS_S + ak] = *(const u32x4*)(B16 + idx);
        }
      } else {
#pragma unroll
        for (int e = 0; e < 8; ++e) {
          u16 v = 0;
          if (gn < N && gk + e < K) v = f2bf(gld(B, boff + idx + e, bf32));
          Bs[ar * LDS_S + ak + e] = v;
        }
      }
    } else {
      int gk = k0 + bk;
      long idx = (long)gk * ldb + n0 + bn;
      u16 tmp[8];
      if (gk < K) {
        if (bf32) {
          f32x4 u = *(const f32x4*)(B32 + idx), v = *(const f32x4*)(B32 + idx + 4);
          tmp[0] = f2bf(u.x); tmp[1] = f2bf(u.y); tmp[2] = f2bf(u.z); tmp[3] = f2bf(u.w);
          tmp[4] = f2bf(v.x); tmp[5] = f2bf(v.y); tmp[6] = f2bf(v.z); tmp[7] = f2bf(v.w);
        } else {
          u32x4 v = *(const u32x4*)(B16 + idx);
          tmp[0] = (u16)(v.x & 0xffff); tmp[1] = (u16)(v.x >> 16);
          tmp[2] = (u16)(v.y & 0xffff); tmp[3] = (u16)(v.y >> 16);
          tmp[4] = (u16)(v.z & 0xffff); tmp[5] = (u16)(v.z >> 16);
          tmp[6] = (u16)(v.w & 0xffff); tmp[7] = (u16)(v.w >> 16);
        }
      } else {
#pragma unroll
        for (int e = 0; e < 8; ++e) tmp[e] = 0;
      }
      int rot = tid & 7;  // spread LDS bank writes
#pragma unroll
      for (int e = 0; e < 8; ++e) {
        int ee = (e + rot) & 7;
        Bs[(bn + ee) * LDS_S + bk] = tmp[ee];
      }
    }
    __syncthreads();
    {
      bf16x8 fa[2], fb[2];
      fa[0] = *(const bf16x8*)&As[(wm +      fm) * LDS_S + fq * 8];
      fa[1] = *(const bf16x8*)&As[(wm + 16 + fm) * LDS_S + fq * 8];
      fb[0] = *(const bf16x8*)&Bs[(wn +      fm) * LDS_S + fq * 8];
      fb[1] = *(const bf16x8*)&Bs[(wn + 16 + fm) * LDS_S + fq * 8];
#pragma unroll
      for (int mt = 0; mt < 2; ++mt)
#pragma unroll
        for (int nt = 0; nt < 2; ++nt)
          acc[mt][nt] = __builtin_amdgcn_mfma_f32_16x16x32_bf16(fa[mt], fb[nt], acc[mt][nt], 0, 0, 0);
    }
    __syncthreads();
  }
  // epilogue: C/D layout col=lane&15, row=(lane>>4)*4+reg (m89-verified)
#pragma unroll
  for (int mt = 0; mt < 2; ++mt)
#pragma unroll
    for (int nt = 0; nt < 2; ++nt)
#pragma unroll
      for (int rr = 0; rr < 4; ++rr) {
        int gm = m0 + wm + mt * 16 + fq * 4 + rr;
        int gn = n0 + wn + nt * 16 + fm;
        if (gm < M && gn < N) {
          float v = alpha * acc[mt][nt][rr];
          if (obf) Cb[(long)zl * sC + (long)gm * ldc + gn] = f2bf(v);
          else     Cf[(long)zl * sC + (long)gm * ldc + gn] = v;
        }
      }
}

// ------------------------------------------------------------- row LN -------
// 8-wide vectorized. N must be a multiple of 8 (768 / 6656 are).
__global__ __launch_bounds__(256) void ln_rows(
    const u16* __restrict__ in, const void* __restrict__ g, const void* __restrict__ b,
    void* __restrict__ out, int N, const int* __restrict__ dtf, int isfinal)
{
  const int f = dtf[0];
  long row = blockIdx.x;
  const u16* ip = in + row * N;
  int tid = threadIdx.x, lane = tid & 63, wave = tid >> 6;
  const int nv = N >> 3;
  float s1 = 0.f, s2 = 0.f;
  for (int c8 = tid; c8 < nv; c8 += 256) {
    u32x4 v = *(const u32x4*)(ip + c8 * 8);
    float e0 = bf2f((u16)(v.x & 0xffff)), e1 = bf2f((u16)(v.x >> 16));
    float e2 = bf2f((u16)(v.y & 0xffff)), e3 = bf2f((u16)(v.y >> 16));
    float e4 = bf2f((u16)(v.z & 0xffff)), e5 = bf2f((u16)(v.z >> 16));
    float e6 = bf2f((u16)(v.w & 0xffff)), e7 = bf2f((u16)(v.w >> 16));
    s1 += ((e0 + e1) + (e2 + e3)) + ((e4 + e5) + (e6 + e7));
    s2 += ((e0*e0 + e1*e1) + (e2*e2 + e3*e3)) + ((e4*e4 + e5*e5) + (e6*e6 + e7*e7));
  }
#pragma unroll
  for (int o = 32; o; o >>= 1) { s1 += __shfl_xor(s1, o, 64); s2 += __shfl_xor(s2, o, 64); }
  __shared__ float red[8];
  if (lane == 0) { red[wave] = s1; red[4 + wave] = s2; }
  __syncthreads();
  s1 = red[0] + red[1] + red[2] + red[3];
  s2 = red[4] + red[5] + red[6] + red[7];
  float mean = s1 / N;
  float var = s2 / N - mean * mean;
  float rstd = rsqrtf(fmaxf(var, 0.f) + 1e-5f);
  for (int c8 = tid; c8 < nv; c8 += 256) {
    int c = c8 * 8;
    u32x4 v = *(const u32x4*)(ip + c);
    float e[8];
    e[0] = bf2f((u16)(v.x & 0xffff)); e[1] = bf2f((u16)(v.x >> 16));
    e[2] = bf2f((u16)(v.y & 0xffff)); e[3] = bf2f((u16)(v.y >> 16));
    e[4] = bf2f((u16)(v.z & 0xffff)); e[5] = bf2f((u16)(v.z >> 16));
    e[6] = bf2f((u16)(v.w & 0xffff)); e[7] = bf2f((u16)(v.w >> 16));
    float gg[8], bb[8];
    if (f) {
      const float* gp = (const float*)g + c; const float* bp = (const float*)b + c;
      f32x4 g0 = *(const f32x4*)gp, g1 = *(const f32x4*)(gp + 4);
      f32x4 b0 = *(const f32x4*)bp, b1 = *(const f32x4*)(bp + 4);
      gg[0]=g0.x; gg[1]=g0.y; gg[2]=g0.z; gg[3]=g0.w; gg[4]=g1.x; gg[5]=g1.y; gg[6]=g1.z; gg[7]=g1.w;
      bb[0]=b0.x; bb[1]=b0.y; bb[2]=b0.z; bb[3]=b0.w; bb[4]=b1.x; bb[5]=b1.y; bb[6]=b1.z; bb[7]=b1.w;
    } else {
      u32x4 gv = *(const u32x4*)((const u16*)g + c);
      u32x4 bv = *(const u32x4*)((const u16*)b + c);
      gg[0]=bf2f((u16)(gv.x&0xffff)); gg[1]=bf2f((u16)(gv.x>>16));
      gg[2]=bf2f((u16)(gv.y&0xffff)); gg[3]=bf2f((u16)(gv.y>>16));
      gg[4]=bf2f((u16)(gv.z&0xffff)); gg[5]=bf2f((u16)(gv.z>>16));
      gg[6]=bf2f((u16)(gv.w&0xffff)); gg[7]=bf2f((u16)(gv.w>>16));
      bb[0]=bf2f((u16)(bv.x&0xffff)); bb[1]=bf2f((u16)(bv.x>>16));
      bb[2]=bf2f((u16)(bv.y&0xffff)); bb[3]=bf2f((u16)(bv.y>>16));
      bb[4]=bf2f((u16)(bv.z&0xffff)); bb[5]=bf2f((u16)(bv.z>>16));
      bb[6]=bf2f((u16)(bv.w&0xffff)); bb[7]=bf2f((u16)(bv.w>>16));
    }
    float o_[8];
#pragma unroll
    for (int e2i = 0; e2i < 8; ++e2i) o_[e2i] = (e[e2i] - mean) * rstd * gg[e2i] + bb[e2i];
    if (isfinal && f) {
      float* op = (float*)out + row * N + c;
      f32x4 o0 = {o_[0], o_[1], o_[2], o_[3]}, o1 = {o_[4], o_[5], o_[6], o_[7]};
      *(f32x4*)op = o0; *(f32x4*)(op + 4) = o1;
    } else {
      u32x4 q = { (u32)f2bf(o_[0]) | ((u32)f2bf(o_[1]) << 16),
                  (u32)f2bf(o_[2]) | ((u32)f2bf(o_[3]) << 16),
                  (u32)f2bf(o_[4]) | ((u32)f2bf(o_[5]) << 16),
                  (u32)f2bf(o_[6]) | ((u32)f2bf(o_[7]) << 16) };
      *(u32x4*)((u16*)out + row * N + c) = q;
    }
  }
}

// ------------------------------------------------------------- wbar ---------
__global__ __launch_bounds__(256) void wbar_k(const void* __restrict__ Wconv,
                                              float* __restrict__ wbar,
                                              const int* __restrict__ dtf)
{
  const int f = dtf[0];
  int r = blockIdx.x * 4 + (threadIdx.x >> 6);   // row 0..6655 = g*64+l
  int lane = threadIdx.x & 63;
  long base = (long)r * 768;
  float s = 0.f;
  for (int c = lane; c < 768; c += 64) s += gld(Wconv, base + c, f);
#pragma unroll
  for (int o = 32; o; o >>= 1) s += __shfl_xor(s, o, 64);
  if (lane == 0) wbar[r] = s * (1.f / 768.f);
}

// ------------------------------------------------------------- stats2 -------
__global__ __launch_bounds__(256) void stats2_k(
    const u16* __restrict__ midbf, const u16* __restrict__ Y, const float* __restrict__ wbar,
    u16* __restrict__ midi, float* __restrict__ pim, int c)
{
  int g = blockIdx.y;
  int r = blockIdx.x * 4 + (threadIdx.x >> 6);
  if (r >= 514) return;
  int lane = threadIdx.x & 63;
  int R = c * 514 + r;
  int b = R / 257, j = R - b * 257;
  float m = bf2f(midbf[(long)R * 6656 + g * 64 + lane]);
  float y = bf2f(Y[((long)g * 514 + r) * 64 + lane]);
  float wb = wbar[g * 64 + lane];
  float mup = m * wb, q2p = m * y;
#pragma unroll
  for (int o = 32; o; o >>= 1) { mup += __shfl_xor(mup, o, 64); q2p += __shfl_xor(q2p, o, 64); }
  float var = q2p - mup * mup;
  float inv = rsqrtf(fmaxf(var, 0.f) + 1e-5f);
  long base = ((long)b * 104 + g) * 257 + j;
  midi[base * 64 + lane] = f2bf(inv * m);
  if (lane == 0) pim[base] = inv * mup;
}

// ------------------------------------------------------------- softmax ------
__global__ __launch_bounds__(256) void softmax_k(
    const float* __restrict__ simf, const float* __restrict__ pim,
    u16* __restrict__ Abf, u16* __restrict__ A2bf, float* __restrict__ s_sh)
{
  int bh = blockIdx.x;
  int b = bh / 6, h = bh - b * 6;
  int tid = threadIdx.x, lane = tid & 63, wave = tid >> 6;
  int i = blockIdx.y * 4 + wave;
  int g = i % 104, rq = i / 104;
  const float* sp_ = simf + ((long)bh * 416 + i) * 257;
  float s[5];
#pragma unroll
  for (int jc = 0; jc < 5; ++jc) {
    int j = jc * 64 + lane;
    s[jc] = (j < 257) ? sp_[j] : -1e30f;
  }
  float mx = -1e30f;
#pragma unroll
  for (int jc = 0; jc < 5; ++jc) mx = fmaxf(mx, s[jc]);
#pragma unroll
  for (int o = 32; o; o >>= 1) mx = fmaxf(mx, __shfl_xor(mx, o, 64));
  float p[5], sum = 0.f, sp = 0.f;
  long pimb = ((long)b * 104 + g) * 257;
#pragma unroll
  for (int jc = 0; jc < 5; ++jc) {
    int j = jc * 64 + lane;
    float pv = 0.f;
    if (j < 257) { pv = __expf(s[jc] - mx); sp = fmaf(pv, pim[pimb + j], sp); }
    p[jc] = pv; sum += pv;
  }
#pragma unroll
  for (int o = 32; o; o >>= 1) { sum += __shfl_xor(sum, o, 64); sp += __shfl_xor(sp, o, 64); }
  float rs = 1.f / sum;
  long arow  = ((long)bh * 416 + i) * 264;
  long a2row = (((long)b * 104 + g) * 24 + h * 4 + rq) * 264;
#pragma unroll
  for (int jc = 0; jc < 5; ++jc) {
    int j = jc * 64 + lane;
    if (j < 257) { u16 pb = f2bf(p[jc] * rs); Abf[arow + j] = pb; A2bf[a2row + j] = pb; }
    else if (j < 264) { Abf[arow + j] = 0; A2bf[a2row + j] = 0; }
  }
  if (lane == 0) s_sh[(long)bh * 416 + i] = sp * rs;
}

// ------------------------------------------------------------- combine ------
__global__ __launch_bounds__(256) void combine_k(
    const u16* __restrict__ O, const float* __restrict__ s_sh, const float* __restrict__ c_buf,
    const void* __restrict__ gv2, const void* __restrict__ bv2,
    u16* __restrict__ opbf, const int* __restrict__ dtf)
{
  const int f = dtf[0];
  int bi = blockIdx.x;
  int b = bi / 416, i = bi - b * 416;
  int g = i % 104, rq = i / 104;
  int tid = threadIdx.x;
  long obase = ((long)b * 104 + g) * 24 * 768;
#pragma unroll
  for (int it = 0; it < 3; ++it) {
    int d = tid + it * 256;
    int h = d >> 7, dh = d & 127;
    float o = bf2f(O[obase + (long)(h * 4 + rq) * 768 + d]);
    float ssh = s_sh[((long)b * 6 + h) * 416 + i];
    float val = gld(gv2, d, f) * (o - ssh) + gld(bv2, d, f)
              + c_buf[(((long)b * 6 + h) * 416 + i) * 128 + dh];
    opbf[((long)b * 416 + i) * 768 + d] = f2bf(val);
  }
}

// ---------------------------------------------------------------- host ------
static void launch_gemm(const void* A, const void* B, float* Cf, u16* Cb, int obf,
                        int M, int N, int K, int lda, int ldb, int ldc,
                        long sAo, long sAi, int adiv, long sBo, long sBi, int bdiv,
                        long sC, int zoff, int Z, int btrans, float alpha,
                        const int* dtf, int aSel, int bSel, hipStream_t st)
{
  dim3 grid((M + 63) / 64, (N + 63) / 64, Z);
  gemm_bf16<<<grid, dim3(256), 0, st>>>(A, B, Cf, Cb, obf, M, N, K, lda, ldb, ldc,
                                        sAo, sAi, adiv, sBo, sBi, bdiv,
                                        sC, zoff, btrans, alpha, dtf, aSel, bSel);
}

static void launch_gemm128(const u16* A, const u16* B, u16* C,
                           int M, int N, int K, hipStream_t st)
{
  dim3 grid((M + 127) / 128, N / 128, 1);
  gemm128<<<grid, dim3(256), 0, st>>>(A, B, C, M, N, K, K, K, N);
}

extern "C" void kernel_launch(void* const* d_in, const int* in_sizes, int n_in,
                              void* d_out, int out_size, void* d_ws, size_t ws_size,
                              hipStream_t stream)
{
  (void)in_sizes; (void)n_in;
  const void* x   = d_in[0];
  const void* ctx = d_in[1];
  const void* Wq  = d_in[2];
  const void* gq  = d_in[3];
  const void* bq  = d_in[4];
  const void* Wk  = d_in[5];
  const void* gk  = d_in[6];
  const void* bk  = d_in[7];
  const void* Wv  = d_in[8];
  const void* gv1 = d_in[9];
  const void* bv1 = d_in[10];
  const void* Wcv = d_in[11];
  const void* gv2 = d_in[12];
  const void* bv2 = d_in[13];
  const void* Wo  = d_in[14];
  const void* go  = d_in[15];
  const void* bo  = d_in[16];

  // -------- workspace layout (unchanged from R9, known-safe) --------
  const size_t SZ_FLAG = 256;
  const size_t SZ_QBF  = 2555904;
  const size_t SZ_KBF  = 1579008;
  const size_t SZ_MID  = 13684736;
  const size_t SZ_MM   = 1703936;
  const size_t SZ_WB   = 26624;
  const size_t SZ_MIDI = 13684736;
  const size_t SZ_PIM  = 427648;
  const size_t SZ_ABF  = 5271552;
  const size_t SZ_A2   = 5271552;
  const size_t SZ_SSH  = 39936;
  const size_t SZ_CB   = 1579008;
  const size_t REQUIRED = SZ_FLAG + SZ_QBF + SZ_KBF + SZ_MID + SZ_MM + SZ_WB +
                          SZ_MIDI + SZ_PIM + SZ_ABF + SZ_A2 + SZ_SSH + SZ_CB;  // 45,824,896

  if (ws_size < REQUIRED) {
    fill_k<<<(out_size + 255) / 256, 256, 0, stream>>>((u16*)d_out, (float)(ws_size >> 20), out_size);
    return;
  }

  char* p = (char*)d_ws;
  int*   dtf   = (int*)  p;                 p += SZ_FLAG;
  u16*   qbf   = (u16*)  p;                 p += SZ_QBF;
  u16*   kbf   = (u16*)  p;                 p += SZ_KBF;
  char*  midrg = p;                         p += SZ_MID;
  char*  mmrg  = p;                         p += SZ_MM;
  float* wbar  = (float*)p;                 p += SZ_WB;
  u16*   midi  = (u16*)  p;                 p += SZ_MIDI;
  float* pim   = (float*)p;                 p += SZ_PIM;
  char*  abfrg = p;                         p += SZ_ABF;
  u16*   A2bf  = (u16*)  p;                 p += SZ_A2;
  float* s_sh  = (float*)p;                 p += SZ_SSH;
  u16*   cb    = (u16*)  p;                 p += SZ_CB;

  u16*   WqT   = (u16*)midrg;
  u16*   WkT   = (u16*)midrg;
  u16*   midbf = (u16*)midrg;
  float* simf  = (float*)midrg;
  float* c_buf = (float*)midrg;
  u16*   Tb16  = (u16*)(midrg + 5111808);
  u16*   WoT   = (u16*)(midrg + 5111808);
  u16*   Gb    = (u16*)mmrg;
  u16*   Obf   = (u16*)mmrg;
  u16*   xb    = (u16*)abfrg;
  u16*   WvT   = (u16*)abfrg;
  u16*   Ybuf  = (u16*)abfrg;
  u16*   Abf   = (u16*)abfrg;
  u16*   opbf  = (u16*)abfrg;

  probe_k<<<1, 256, 0, stream>>>((const u32*)x, dtf);

  // ---- prep: bf16 copies / transposes ----
  convb_k<<<(1277952 / 8 + 255) / 256, 256, 0, stream>>>(x, xb, 1277952, dtf);
  convb_k<<<(789504 / 8 + 255) / 256, 256, 0, stream>>>(ctx, cb, 789504, dtf);
  transb_k<<<dim3(24, 24), 256, 0, stream>>>(Wq, WqT, 768, 768, dtf);

  // q = LN(x @ Wq)
  launch_gemm128(xb, WqT, qbf, 1664, 768, 768, stream);
  ln_rows<<<1664, 256, 0, stream>>>(qbf, gq, bq, qbf, 768, dtf, 0);

  transb_k<<<dim3(24, 24), 256, 0, stream>>>(Wk, WkT, 768, 768, dtf);
  // k = LN(ctx @ Wk)
  launch_gemm128(cb, WkT, kbf, 1028, 768, 768, stream);
  ln_rows<<<1028, 256, 0, stream>>>(kbf, gk, bk, kbf, 768, dtf, 0);

  transb_k<<<dim3(208, 24), 256, 0, stream>>>(Wv, WvT, 768, 6656, dtf);
  // mid = LN(ctx @ Wv)
  launch_gemm128(cb, WvT, midbf, 1028, 6656, 768, stream);
  ln_rows<<<1028, 256, 0, stream>>>(midbf, gv1, bv1, midbf, 6656, dtf, 0);

  // Gram: M[g] = Wconv[g] @ Wconv[g]^T / 768  (z=104, flag loads, bf16 out)
  launch_gemm(Wcv, Wcv, nullptr, Gb, 1, 64, 64, 768, 768, 768, 64,
              49152, 0, 1, 49152, 0, 1, 4096, 0, 104, 1, 1.f / 768.f, dtf, 1, 1, stream);
  wbar_k<<<1664, 256, 0, stream>>>(Wcv, wbar, dtf);
  // stats via MFMA: Y = mid_g @ M[g], 2 chunks of 514 rows
  for (int c = 0; c < 2; ++c) {
    launch_gemm(midbf + (long)c * 514 * 6656, Gb, nullptr, Ybuf, 1,
                514, 64, 64, 6656, 64, 64,
                0, 64, 104, 4096, 0, 1, 32896, 0, 104, 1, 1.f, dtf, 0, 0, stream);
    stats2_k<<<dim3(129, 104), 256, 0, stream>>>(midbf, Ybuf, wbar, midi, pim, c);
  }

  // sim = scale^2 * q @ k^T   (z = b*6+h, btrans, fp32 out)
  launch_gemm(qbf, kbf, simf, nullptr, 0, 416, 257, 128, 768, 768, 257,
              319488, 128, 6, 197376, 128, 6, 106912, 0, 24, 1,
              0.08838834764831845f, dtf, 0, 0, stream);
  softmax_k<<<dim3(24, 104), 256, 0, stream>>>(simf, pim, Abf, A2bf, s_sh);

  // c = A @ ctx_head   (z = b*6+h; B = cb bf16)
  launch_gemm(Abf, cb, c_buf, nullptr, 0, 416, 128, 257, 264, 768, 128,
              109824, 0, 1, 197376, 128, 6, 53248, 0, 24, 0, 1.f, dtf, 0, 0, stream);
  // T = A2 @ midi      (z = b*104+g)
  launch_gemm(A2bf, midi, nullptr, Tb16, 1, 24, 64, 257, 264, 64, 64,
              6336, 0, 1, 16448, 0, 1, 1536, 0, 416, 0, 1.f, dtf, 0, 0, stream);
  // O = T @ Wconv[g]   (z = b*104+g, flag B loads)
  launch_gemm(Tb16, Wcv, nullptr, Obf, 1, 24, 768, 64, 64, 768, 768,
              1536, 0, 1, 0, 49152, 104, 18432, 0, 416, 0, 1.f, dtf, 0, 1, stream);

  transb_k<<<dim3(24, 24), 256, 0, stream>>>(Wo, WoT, 768, 768, dtf);  // Tb16 dead after O
  combine_k<<<1664, 256, 0, stream>>>(Obf, s_sh, c_buf, gv2, bv2, opbf, dtf);
  // out = LN(out_pre @ Wo): GEMM -> qbf scratch, LN -> d_out (flag dtype)
  launch_gemm128(opbf, WoT, qbf, 1664, 768, 768, stream);
  ln_rows<<<1664, 256, 0, stream>>>(qbf, go, bo, d_out, 768, dtf, 1);
}